// Round 3
// baseline (1122.576 us; speedup 1.0000x reference)
//
#include <hip/hip_runtime.h>
#include <math.h>

#define NN 8192
#define ELL_W 128

__device__ __forceinline__ float lrelu(float x) { return x > 0.f ? x : 0.01f * x; }

// ---------------- ELL build: adj (8192x8192 f32, values 0/1) -> col idx + cnt + deg --------
// One wave per row, 4 rows/block, float4 loads (1KB/wave/instr). ELL entries are NOT
// column-sorted (order irrelevant: fp32 gather-sum order differs from JAX dense regardless).
__global__ void build_ell_kernel(const float* __restrict__ adj, int* __restrict__ ell,
                                 int* __restrict__ cnt, float* __restrict__ deg) {
    const int row  = blockIdx.x * 4 + (threadIdx.x >> 6);
    const int lane = threadIdx.x & 63;
    const float4* arow = (const float4*)(adj + (size_t)row * NN);
    const unsigned long long lmask = (1ull << lane) - 1ull;
    int count = 0;
    for (int c0 = 0; c0 < NN; c0 += 256) {
        const float4 v = arow[(c0 >> 2) + lane];
        const int col = c0 + lane * 4;
        float f[4] = {v.x, v.y, v.z, v.w};
        #pragma unroll
        for (int q = 0; q < 4; ++q) {
            unsigned long long m = __ballot(f[q] > 0.f);
            if (f[q] > 0.f) {
                int pos = count + __popcll(m & lmask);
                if (pos < ELL_W) ell[row * ELL_W + pos] = col + q;
            }
            count += __popcll(m);
        }
    }
    if (lane == 0) {
        cnt[row] = count < ELL_W ? count : ELL_W;  // P(n>128) ~ 1e-42/row, negligible
        deg[row] = (float)count;                   // adj values are exactly 1.0f
    }
}

__global__ void zero_accum_kernel(float* accum) {
    accum[0] = 0.f; accum[1] = 0.f;
}

// ---------------- fp32 GEMM: C = act(A@B (+bias)) ------------------------------------------
// Tile BM=PM*16 x BN=PN*16, 256 threads, per-thread PM x PN. <8,8>: 128x128, 4 ds_read_b128
// per 64 FMAs. A: MxK row-major. B: KxN (BT=0) or NxK (BT=1, PN=4 only). ACT1 = sigmoid+bias.
// Epilogue stores scalar (two d_out regions sit at +4B offsets; stores are a tiny fraction).
template <int PM, int PN, int BT, int ACT>
__global__ void gemm_kernel(const float* __restrict__ A, const float* __restrict__ B,
                            const float* __restrict__ bias, float* __restrict__ C,
                            int M, int K, int N) {
    constexpr int BM = PM * 16;
    constexpr int BN = PN * 16;
    __shared__ __align__(16) float As[16][BM + 4];
    __shared__ __align__(16) float Bs[16][BN + 4];
    const int tid = threadIdx.x;
    const int tx = tid & 15, ty = tid >> 4;
    const int bm = blockIdx.y * BM;
    const int bn = blockIdx.x * BN;
    float acc[PM][PN] = {};
    for (int k0 = 0; k0 < K; k0 += 16) {
        #pragma unroll
        for (int e = 0; e < BM / 64; ++e) {        // A tile BMx16 = BM*4 float4
            int idx = tid + e * 256;
            int m = idx >> 2, q = idx & 3;
            const float4 av = *(const float4*)(A + (size_t)(bm + m) * K + k0 + q * 4);
            As[q * 4 + 0][m] = av.x; As[q * 4 + 1][m] = av.y;
            As[q * 4 + 2][m] = av.z; As[q * 4 + 3][m] = av.w;
        }
        if (BT == 0) {                             // B tile 16xBN = BN*4 float4
            #pragma unroll
            for (int e = 0; e < BN / 64; ++e) {
                int idx = tid + e * 256;
                int kk = idx / (BN / 4), nq = idx % (BN / 4);
                const float4 bv = *(const float4*)(B + (size_t)(k0 + kk) * N + bn + nq * 4);
                *(float4*)&Bs[kk][nq * 4] = bv;
            }
        } else {                                   // B^T (NxK): PN==4 path only
            #pragma unroll
            for (int e = 0; e < BN / 64; ++e) {
                int idx = tid + e * 256;
                int n = idx >> 2, q = idx & 3;
                const float4 bv = *(const float4*)(B + (size_t)(bn + n) * K + k0 + q * 4);
                Bs[q * 4 + 0][n] = bv.x; Bs[q * 4 + 1][n] = bv.y;
                Bs[q * 4 + 2][n] = bv.z; Bs[q * 4 + 3][n] = bv.w;
            }
        }
        __syncthreads();
        #pragma unroll
        for (int kk = 0; kk < 16; ++kk) {
            float a[PM], b[PN];
            #pragma unroll
            for (int e = 0; e < PM / 4; ++e)
                *(float4*)&a[e * 4] = *(const float4*)&As[kk][ty * PM + e * 4];
            #pragma unroll
            for (int e = 0; e < PN / 4; ++e)
                *(float4*)&b[e * 4] = *(const float4*)&Bs[kk][tx * PN + e * 4];
            #pragma unroll
            for (int i = 0; i < PM; ++i)
                #pragma unroll
                for (int j = 0; j < PN; ++j)
                    acc[i][j] = fmaf(a[i], b[j], acc[i][j]);
        }
        __syncthreads();
    }
    #pragma unroll
    for (int i = 0; i < PM; ++i) {
        size_t m = (size_t)(bm + ty * PM + i);
        #pragma unroll
        for (int j = 0; j < PN; ++j) {
            float v = acc[i][j];
            int n = bn + tx * PN + j;
            if (ACT == 1) { v += bias[n]; v = 1.f / (1.f + __expf(-v)); }
            C[m * N + n] = v;
        }
    }
}

// ---------------- adj @ M gather-sum + bias + lrelu (float4 per lane) -----------------------
template <int C>
__global__ void spmm_kernel(const float* __restrict__ M, const int* __restrict__ ell,
                            const int* __restrict__ cnt, const float* __restrict__ bias,
                            float* __restrict__ out, float* __restrict__ out2) {
    constexpr int TPR = C / 4;
    constexpr int RPB = 256 / TPR;
    const int rid = threadIdx.x / TPR;
    const int c4  = threadIdx.x % TPR;
    const int row = blockIdx.x * RPB + rid;
    __shared__ int nb_s[RPB][ELL_W];
    const int n = cnt[row];
    for (int t = c4; t < n; t += TPR) nb_s[rid][t] = ell[row * ELL_W + t];
    __syncthreads();
    float4 acc = {0.f, 0.f, 0.f, 0.f};
    for (int t = 0; t < n; ++t) {
        const float4 v = *(const float4*)(M + (size_t)nb_s[rid][t] * C + c4 * 4);
        acc.x += v.x; acc.y += v.y; acc.z += v.z; acc.w += v.w;
    }
    const float4 bv = *(const float4*)(bias + c4 * 4);
    float4 r;
    r.x = lrelu(acc.x + bv.x); r.y = lrelu(acc.y + bv.y);
    r.z = lrelu(acc.z + bv.z); r.w = lrelu(acc.w + bv.w);
    *(float4*)(out + (size_t)row * C + c4 * 4) = r;
    if (out2) {                                    // +4B-misaligned d_out region: scalar
        size_t o = (size_t)row * C + c4 * 4;
        out2[o] = r.x; out2[o + 1] = r.y; out2[o + 2] = r.z; out2[o + 3] = r.w;
    }
}

// ---------------- f1 = seq@a1, f2 = seq@a2 --------------------------------------------------
__global__ void f12_kernel(const float* __restrict__ seq, const float* __restrict__ a1,
                           const float* __restrict__ a2, float* __restrict__ f1,
                           float* __restrict__ f2) {
    const int row = blockIdx.x * 4 + (threadIdx.x >> 6);
    const int lane = threadIdx.x & 63;
    const float4 v  = *(const float4*)(seq + (size_t)row * 256 + lane * 4);
    const float4 w1 = *(const float4*)(a1 + lane * 4);
    const float4 w2 = *(const float4*)(a2 + lane * 4);
    float s1 = v.x * w1.x + v.y * w1.y + v.z * w1.z + v.w * w1.w;
    float s2 = v.x * w2.x + v.y * w2.y + v.z * w2.z + v.w * w2.w;
    #pragma unroll
    for (int o = 32; o; o >>= 1) { s1 += __shfl_xor(s1, o); s2 += __shfl_xor(s2, o); }
    if (lane == 0) { f1[row] = s1; f2[row] = s2; }
}

// ---------------- sparse GAT: neighbor softmax + weighted float4 gather ---------------------
// One wave per row. Non-neighbor exp(x-1e9-max) == 0.0f exactly in fp32, so neighbor-only
// softmax is bit-equivalent in support to the reference's dense masked softmax.
__global__ void attn_kernel(const float* __restrict__ seq, const int* __restrict__ ell,
                            const int* __restrict__ cnt, const float* __restrict__ f1,
                            const float* __restrict__ f2, float* __restrict__ out) {
    const int wid = threadIdx.x >> 6, lane = threadIdx.x & 63;
    const int row = blockIdx.x * 4 + wid;
    __shared__ int   nb_s[4][ELL_W];
    __shared__ float cf_s[4][ELL_W];
    const int n = cnt[row];
    const float f1r = f1[row];
    float m = -3.0e38f;
    for (int t = lane; t < n; t += 64) {
        int j = ell[row * ELL_W + t];
        nb_s[wid][t] = j;
        float v = lrelu(f1r + f2[j]);
        cf_s[wid][t] = v;
        m = fmaxf(m, v);
    }
    #pragma unroll
    for (int o = 32; o; o >>= 1) m = fmaxf(m, __shfl_xor(m, o));
    __syncthreads();
    float s = 0.f;
    for (int t = lane; t < n; t += 64) {
        float e = __expf(cf_s[wid][t] - m);
        cf_s[wid][t] = e;
        s += e;
    }
    #pragma unroll
    for (int o = 32; o; o >>= 1) s += __shfl_xor(s, o);
    const float inv = 1.f / s;
    __syncthreads();
    float4 acc = {0.f, 0.f, 0.f, 0.f};
    for (int t = 0; t < n; ++t) {
        const float c = cf_s[wid][t];
        const float4 v = *(const float4*)(seq + (size_t)nb_s[wid][t] * 256 + lane * 4);
        acc.x = fmaf(c, v.x, acc.x); acc.y = fmaf(c, v.y, acc.y);
        acc.z = fmaf(c, v.z, acc.z); acc.w = fmaf(c, v.w, acc.w);
    }
    float4 r;
    r.x = lrelu(acc.x * inv); r.y = lrelu(acc.y * inv);
    r.z = lrelu(acc.z * inv); r.w = lrelu(acc.w * inv);
    *(float4*)(out + (size_t)row * 256 + lane * 4) = r;
}

// ---------------- losses --------------------------------------------------------------------
__global__ void loss_res_kernel(const float* __restrict__ X, const float* __restrict__ Xr,
                                float* __restrict__ accum) {
    __shared__ float sred[256];
    float local = 0.f;
    const size_t total4 = (size_t)NN * 1024 / 4;
    for (size_t i = (size_t)blockIdx.x * 256 + threadIdx.x; i < total4; i += (size_t)gridDim.x * 256) {
        const float4 x = ((const float4*)X)[i];
        float xr0 = Xr[i * 4 + 0], xr1 = Xr[i * 4 + 1], xr2 = Xr[i * 4 + 2], xr3 = Xr[i * 4 + 3];
        float d;
        d = (xr0 - x.x) * fmaf(x.x, 24.f, 1.f); local = fmaf(d, d, local);
        d = (xr1 - x.y) * fmaf(x.y, 24.f, 1.f); local = fmaf(d, d, local);
        d = (xr2 - x.z) * fmaf(x.z, 24.f, 1.f); local = fmaf(d, d, local);
        d = (xr3 - x.w) * fmaf(x.w, 24.f, 1.f); local = fmaf(d, d, local);
    }
    sred[threadIdx.x] = local; __syncthreads();
    for (int s = 128; s; s >>= 1) { if (threadIdx.x < s) sred[threadIdx.x] += sred[threadIdx.x + s]; __syncthreads(); }
    if (threadIdx.x == 0) atomicAdd(accum, sred[0]);
}

__global__ void loss_emb_kernel(const float* __restrict__ H, const int* __restrict__ ell,
                                const int* __restrict__ cnt, const float* __restrict__ deg,
                                float* __restrict__ accum) {
    const int row = blockIdx.x, tid = threadIdx.x;  // 128 threads
    __shared__ int nb[ELL_W];
    __shared__ float sred[128];
    const int n = cnt[row];
    if (tid < n) nb[tid] = ell[row * ELL_W + tid];
    __syncthreads();
    float hv = H[(size_t)row * 128 + tid];
    float g = 0.f;
    for (int t = 0; t < n; ++t) g += H[(size_t)nb[t] * 128 + tid];
    float lh = deg[row] * hv - g;
    sred[tid] = hv * lh; __syncthreads();
    for (int s = 64; s; s >>= 1) { if (tid < s) sred[tid] += sred[tid + s]; __syncthreads(); }
    if (tid == 0) atomicAdd(accum + 1, sred[0]);
}

__global__ void finalize_kernel(const float* __restrict__ accum, float* __restrict__ out) {
    // loss = ALPHA*loss_res + BETA*2*sum(H*LH); ALPHA=100, BETA=1
    out[0] = 100.f * accum[0] + 2.f * accum[1];
}

// ---------------- driver --------------------------------------------------------------------
extern "C" void kernel_launch(void* const* d_in, const int* in_sizes, int n_in,
                              void* d_out, int out_size, void* d_ws, size_t ws_size,
                              hipStream_t stream) {
    const float* X      = (const float*)d_in[0];
    const float* adj    = (const float*)d_in[1];
    const float* W0     = (const float*)d_in[2];
    const float* b0     = (const float*)d_in[3];
    const float* W1     = (const float*)d_in[4];
    const float* b1     = (const float*)d_in[5];
    const float* W2     = (const float*)d_in[6];
    const float* b2     = (const float*)d_in[7];
    const float* attn_W = (const float*)d_in[8];
    const float* a1     = (const float*)d_in[9];
    const float* a2     = (const float*)d_in[10];
    const float* dW0    = (const float*)d_in[11];
    const float* db0    = (const float*)d_in[12];
    const float* dW1    = (const float*)d_in[13];
    const float* db1    = (const float*)d_in[14];
    const float* dW2    = (const float*)d_in[15];
    const float* db2    = (const float*)d_in[16];

    float* out  = (float*)d_out;
    float* Hout = out + 1;                       // 4B-aligned only -> scalar stores
    float* Xr   = out + 1 + (size_t)NN * 128;    // 4B-aligned only -> scalar stores

    char* w = (char*)d_ws;
    int*   ell   = (int*)w;   w += (size_t)NN * ELL_W * 4;   // 4 MiB
    int*   cnt   = (int*)w;   w += (size_t)NN * 4;
    float* deg   = (float*)w; w += (size_t)NN * 4;
    float* f1    = (float*)w; w += (size_t)NN * 4;
    float* f2    = (float*)w; w += (size_t)NN * 4;
    float* accum = (float*)w; w += 256;
    float* bufA  = (float*)w; w += (size_t)NN * 512 * 4;     // 16 MiB
    float* bufB  = (float*)w; w += (size_t)NN * 512 * 4;     // 16 MiB
    float* bufC  = (float*)w; w += (size_t)NN * 256 * 4;     // 8 MiB
    float* bufH  = (float*)w; w += (size_t)NN * 128 * 4;     // 4 MiB (aligned copy of H)

    build_ell_kernel<<<dim3(NN / 4), dim3(256), 0, stream>>>(adj, ell, cnt, deg);
    zero_accum_kernel<<<1, 1, 0, stream>>>(accum);

    // 1. XW0 = X @ W0   (8192x1024x512) — 128x128 tile, 8x8/thr
    gemm_kernel<8, 8, 0, 0><<<dim3(512 / 128, NN / 128), 256, 0, stream>>>(X, W0, nullptr, bufA, NN, 1024, 512);
    // 2. h0 = lrelu(adj@XW0 + b0)
    spmm_kernel<512><<<NN / 2, 256, 0, stream>>>(bufA, ell, cnt, b0, bufB, nullptr);
    // 3. T1 = h0 @ W1   (8192x512x256)
    gemm_kernel<8, 4, 0, 0><<<dim3(256 / 64, NN / 128), 256, 0, stream>>>(bufB, W1, nullptr, bufC, NN, 512, 256);
    // 4. h1 = lrelu(adj@T1 + b1)
    spmm_kernel<256><<<NN / 4, 256, 0, stream>>>(bufC, ell, cnt, b1, bufA, nullptr);
    // 5. seq_fts = h1 @ attn_W^T   (8192x256x256, NT)
    gemm_kernel<8, 4, 1, 0><<<dim3(256 / 64, NN / 128), 256, 0, stream>>>(bufA, attn_W, nullptr, bufB, NN, 256, 256);
    // 6. f1, f2
    f12_kernel<<<NN / 4, 256, 0, stream>>>(bufB, a1, a2, f1, f2);
    // 7. h2 = lrelu(softmax_nb(lrelu(f1+f2)) @ seq_fts)
    attn_kernel<<<NN / 4, 256, 0, stream>>>(bufB, ell, cnt, f1, f2, bufC);
    // 8. T2 = h2 @ W2   (8192x256x128) — 64x64 tile for block count
    gemm_kernel<4, 4, 0, 0><<<dim3(128 / 64, NN / 64), 256, 0, stream>>>(bufC, W2, nullptr, bufA, NN, 256, 128);
    // 9. H = lrelu(adj@T2 + b2) -> aligned bufH + d_out H region
    spmm_kernel<128><<<NN / 8, 256, 0, stream>>>(bufA, ell, cnt, b2, bufH, Hout);
    // 10. Xr0 = sigmoid(H @ dW0 + db0)   (8192x128x256) — small K: 64x64 tile
    gemm_kernel<4, 4, 0, 1><<<dim3(256 / 64, NN / 64), 256, 0, stream>>>(bufH, dW0, db0, bufA, NN, 128, 256);
    // 11. Xr1 = sigmoid(Xr0 @ dW1 + db1) (8192x256x512) — 128x128 tile
    gemm_kernel<8, 8, 0, 1><<<dim3(512 / 128, NN / 128), 256, 0, stream>>>(bufA, dW1, db1, bufB, NN, 256, 512);
    // 12. Xr = sigmoid(Xr1 @ dW2 + db2)  (8192x512x1024) — 128x128 tile -> d_out
    gemm_kernel<8, 8, 0, 1><<<dim3(1024 / 128, NN / 128), 256, 0, stream>>>(bufB, dW2, db2, Xr, NN, 512, 1024);
    // 13. losses
    loss_res_kernel<<<1024, 256, 0, stream>>>(X, Xr, accum);
    loss_emb_kernel<<<NN, 128, 0, stream>>>(bufH, ell, cnt, deg, accum);
    finalize_kernel<<<1, 1, 0, stream>>>(accum, out);
}

// Round 4
// 1042.762 us; speedup vs baseline: 1.0765x; 1.0765x over previous
//
#include <hip/hip_runtime.h>
#include <math.h>

#define NN 8192
#define ELL_W 128

__device__ __forceinline__ float lrelu(float x) { return x > 0.f ? x : 0.01f * x; }

// ---------------- ELL build: adj (8192x8192 f32, values 0/1) -> col idx + cnt + deg --------
// One wave per row, 4 rows/block, float4 loads (1KB/wave/instr). ELL entries are NOT
// column-sorted (order irrelevant: fp32 gather-sum order differs from JAX dense regardless).
__global__ void build_ell_kernel(const float* __restrict__ adj, int* __restrict__ ell,
                                 int* __restrict__ cnt, float* __restrict__ deg) {
    const int row  = blockIdx.x * 4 + (threadIdx.x >> 6);
    const int lane = threadIdx.x & 63;
    const float4* arow = (const float4*)(adj + (size_t)row * NN);
    const unsigned long long lmask = (1ull << lane) - 1ull;
    int count = 0;
    for (int c0 = 0; c0 < NN; c0 += 256) {
        const float4 v = arow[(c0 >> 2) + lane];
        const int col = c0 + lane * 4;
        float f[4] = {v.x, v.y, v.z, v.w};
        #pragma unroll
        for (int q = 0; q < 4; ++q) {
            unsigned long long m = __ballot(f[q] > 0.f);
            if (f[q] > 0.f) {
                int pos = count + __popcll(m & lmask);
                if (pos < ELL_W) ell[row * ELL_W + pos] = col + q;
            }
            count += __popcll(m);
        }
    }
    if (lane == 0) {
        cnt[row] = count < ELL_W ? count : ELL_W;  // P(n>128) ~ 1e-42/row, negligible
        deg[row] = (float)count;                   // adj values are exactly 1.0f
    }
}

__global__ void zero_accum_kernel(float* accum) {
    accum[0] = 0.f; accum[1] = 0.f;
}

// ---------------- fp32 GEMM: C = act(A@B (+bias)), optional fused loss_res ------------------
// Tile BM=PM*16 x BN=PN*16, 256 threads. <8,4>: 128x64 (512-1024 blocks -> 2-4 blocks/CU,
// vs R2's <8,8> 256-block grids that measured 1 block/CU, 35% VALUBusy). <=2-way LDS bank
// conflicts (free) vs <8,8>'s 4-way. ACT1 = sigmoid+bias. LOSS=1 (needs PN=4): fuse
// sum(((C-X)*B)^2) via per-thread accumulate + LDS reduce + 1 atomicAdd/block.
template <int PM, int PN, int BT, int ACT, int LOSS>
__global__ void gemm_kernel(const float* __restrict__ A, const float* __restrict__ B,
                            const float* __restrict__ bias, float* __restrict__ C,
                            int M, int K, int N, const float* __restrict__ Xref,
                            float* __restrict__ accum) {
    constexpr int BM = PM * 16;
    constexpr int BN = PN * 16;
    __shared__ __align__(16) float As[16][BM + 4];
    __shared__ __align__(16) float Bs[16][BN + 4];
    const int tid = threadIdx.x;
    const int tx = tid & 15, ty = tid >> 4;
    const int bm = blockIdx.y * BM;
    const int bn = blockIdx.x * BN;
    float acc[PM][PN] = {};
    for (int k0 = 0; k0 < K; k0 += 16) {
        #pragma unroll
        for (int e = 0; e < BM / 64; ++e) {        // A tile BMx16 = BM*4 float4
            int idx = tid + e * 256;
            int m = idx >> 2, q = idx & 3;
            const float4 av = *(const float4*)(A + (size_t)(bm + m) * K + k0 + q * 4);
            As[q * 4 + 0][m] = av.x; As[q * 4 + 1][m] = av.y;
            As[q * 4 + 2][m] = av.z; As[q * 4 + 3][m] = av.w;
        }
        if (BT == 0) {                             // B tile 16xBN = BN*4 float4
            #pragma unroll
            for (int e = 0; e < BN / 64; ++e) {
                int idx = tid + e * 256;
                int kk = idx / (BN / 4), nq = idx % (BN / 4);
                const float4 bv = *(const float4*)(B + (size_t)(k0 + kk) * N + bn + nq * 4);
                *(float4*)&Bs[kk][nq * 4] = bv;
            }
        } else {                                   // B^T (NxK)
            #pragma unroll
            for (int e = 0; e < BN / 64; ++e) {
                int idx = tid + e * 256;
                int n = idx >> 2, q = idx & 3;
                const float4 bv = *(const float4*)(B + (size_t)(bn + n) * K + k0 + q * 4);
                Bs[q * 4 + 0][n] = bv.x; Bs[q * 4 + 1][n] = bv.y;
                Bs[q * 4 + 2][n] = bv.z; Bs[q * 4 + 3][n] = bv.w;
            }
        }
        __syncthreads();
        #pragma unroll
        for (int kk = 0; kk < 16; ++kk) {
            float a[PM], b[PN];
            #pragma unroll
            for (int e = 0; e < PM / 4; ++e)
                *(float4*)&a[e * 4] = *(const float4*)&As[kk][ty * PM + e * 4];
            #pragma unroll
            for (int e = 0; e < PN / 4; ++e)
                *(float4*)&b[e * 4] = *(const float4*)&Bs[kk][tx * PN + e * 4];
            #pragma unroll
            for (int i = 0; i < PM; ++i)
                #pragma unroll
                for (int j = 0; j < PN; ++j)
                    acc[i][j] = fmaf(a[i], b[j], acc[i][j]);
        }
        __syncthreads();
    }
    float local = 0.f;
    #pragma unroll
    for (int i = 0; i < PM; ++i) {
        size_t m = (size_t)(bm + ty * PM + i);
        float4 xv = {0.f, 0.f, 0.f, 0.f};
        if (LOSS) xv = *(const float4*)(Xref + m * N + bn + tx * PN);  // PN==4, aligned
        #pragma unroll
        for (int j = 0; j < PN; ++j) {
            float v = acc[i][j];
            int n = bn + tx * PN + j;
            if (ACT == 1) { v += bias[n]; v = 1.f / (1.f + __expf(-v)); }
            C[m * N + n] = v;
            if (LOSS) {
                float x = ((const float*)&xv)[j];
                float d = (v - x) * fmaf(x, 24.f, 1.f);   // ETA-1 = 24
                local = fmaf(d, d, local);
            }
        }
    }
    if (LOSS) {
        __shared__ float sred[256];
        sred[tid] = local; __syncthreads();
        for (int s = 128; s; s >>= 1) { if (tid < s) sred[tid] += sred[tid + s]; __syncthreads(); }
        if (tid == 0) atomicAdd(accum, sred[0]);
    }
}

// ---------------- adj @ M gather-sum + bias + lrelu (float4 per lane) -----------------------
template <int C>
__global__ void spmm_kernel(const float* __restrict__ M, const int* __restrict__ ell,
                            const int* __restrict__ cnt, const float* __restrict__ bias,
                            float* __restrict__ out, float* __restrict__ out2) {
    constexpr int TPR = C / 4;
    constexpr int RPB = 256 / TPR;
    const int rid = threadIdx.x / TPR;
    const int c4  = threadIdx.x % TPR;
    const int row = blockIdx.x * RPB + rid;
    __shared__ int nb_s[RPB][ELL_W];
    const int n = cnt[row];
    for (int t = c4; t < n; t += TPR) nb_s[rid][t] = ell[row * ELL_W + t];
    __syncthreads();
    float4 acc = {0.f, 0.f, 0.f, 0.f};
    for (int t = 0; t < n; ++t) {
        const float4 v = *(const float4*)(M + (size_t)nb_s[rid][t] * C + c4 * 4);
        acc.x += v.x; acc.y += v.y; acc.z += v.z; acc.w += v.w;
    }
    const float4 bv = *(const float4*)(bias + c4 * 4);
    float4 r;
    r.x = lrelu(acc.x + bv.x); r.y = lrelu(acc.y + bv.y);
    r.z = lrelu(acc.z + bv.z); r.w = lrelu(acc.w + bv.w);
    *(float4*)(out + (size_t)row * C + c4 * 4) = r;
    if (out2) {                                    // +4B-misaligned d_out region: scalar
        size_t o = (size_t)row * C + c4 * 4;
        out2[o] = r.x; out2[o + 1] = r.y; out2[o + 2] = r.z; out2[o + 3] = r.w;
    }
}

// ---------------- f1 = seq@a1, f2 = seq@a2 --------------------------------------------------
__global__ void f12_kernel(const float* __restrict__ seq, const float* __restrict__ a1,
                           const float* __restrict__ a2, float* __restrict__ f1,
                           float* __restrict__ f2) {
    const int row = blockIdx.x * 4 + (threadIdx.x >> 6);
    const int lane = threadIdx.x & 63;
    const float4 v  = *(const float4*)(seq + (size_t)row * 256 + lane * 4);
    const float4 w1 = *(const float4*)(a1 + lane * 4);
    const float4 w2 = *(const float4*)(a2 + lane * 4);
    float s1 = v.x * w1.x + v.y * w1.y + v.z * w1.z + v.w * w1.w;
    float s2 = v.x * w2.x + v.y * w2.y + v.z * w2.z + v.w * w2.w;
    #pragma unroll
    for (int o = 32; o; o >>= 1) { s1 += __shfl_xor(s1, o); s2 += __shfl_xor(s2, o); }
    if (lane == 0) { f1[row] = s1; f2[row] = s2; }
}

// ---------------- sparse GAT: neighbor softmax + weighted float4 gather ---------------------
// One wave per row. Non-neighbor exp(x-1e9-max) == 0.0f exactly in fp32, so neighbor-only
// softmax is bit-equivalent in support to the reference's dense masked softmax.
__global__ void attn_kernel(const float* __restrict__ seq, const int* __restrict__ ell,
                            const int* __restrict__ cnt, const float* __restrict__ f1,
                            const float* __restrict__ f2, float* __restrict__ out) {
    const int wid = threadIdx.x >> 6, lane = threadIdx.x & 63;
    const int row = blockIdx.x * 4 + wid;
    __shared__ int   nb_s[4][ELL_W];
    __shared__ float cf_s[4][ELL_W];
    const int n = cnt[row];
    const float f1r = f1[row];
    float m = -3.0e38f;
    for (int t = lane; t < n; t += 64) {
        int j = ell[row * ELL_W + t];
        nb_s[wid][t] = j;
        float v = lrelu(f1r + f2[j]);
        cf_s[wid][t] = v;
        m = fmaxf(m, v);
    }
    #pragma unroll
    for (int o = 32; o; o >>= 1) m = fmaxf(m, __shfl_xor(m, o));
    __syncthreads();
    float s = 0.f;
    for (int t = lane; t < n; t += 64) {
        float e = __expf(cf_s[wid][t] - m);
        cf_s[wid][t] = e;
        s += e;
    }
    #pragma unroll
    for (int o = 32; o; o >>= 1) s += __shfl_xor(s, o);
    const float inv = 1.f / s;
    __syncthreads();
    float4 acc = {0.f, 0.f, 0.f, 0.f};
    for (int t = 0; t < n; ++t) {
        const float c = cf_s[wid][t];
        const float4 v = *(const float4*)(seq + (size_t)nb_s[wid][t] * 256 + lane * 4);
        acc.x = fmaf(c, v.x, acc.x); acc.y = fmaf(c, v.y, acc.y);
        acc.z = fmaf(c, v.z, acc.z); acc.w = fmaf(c, v.w, acc.w);
    }
    float4 r;
    r.x = lrelu(acc.x * inv); r.y = lrelu(acc.y * inv);
    r.z = lrelu(acc.z * inv); r.w = lrelu(acc.w * inv);
    *(float4*)(out + (size_t)row * 256 + lane * 4) = r;
}

// ---------------- loss_emb: 2*sum(H*(deg*H - adj@H)) ----------------------------------------
__global__ void loss_emb_kernel(const float* __restrict__ H, const int* __restrict__ ell,
                                const int* __restrict__ cnt, const float* __restrict__ deg,
                                float* __restrict__ accum) {
    const int row = blockIdx.x, tid = threadIdx.x;  // 128 threads
    __shared__ int nb[ELL_W];
    __shared__ float sred[128];
    const int n = cnt[row];
    if (tid < n) nb[tid] = ell[row * ELL_W + tid];
    __syncthreads();
    float hv = H[(size_t)row * 128 + tid];
    float g = 0.f;
    for (int t = 0; t < n; ++t) g += H[(size_t)nb[t] * 128 + tid];
    float lh = deg[row] * hv - g;
    sred[tid] = hv * lh; __syncthreads();
    for (int s = 64; s; s >>= 1) { if (tid < s) sred[tid] += sred[tid + s]; __syncthreads(); }
    if (tid == 0) atomicAdd(accum + 1, sred[0]);
}

__global__ void finalize_kernel(const float* __restrict__ accum, float* __restrict__ out) {
    // loss = ALPHA*loss_res + BETA*2*sum(H*LH); ALPHA=100, BETA=1
    out[0] = 100.f * accum[0] + 2.f * accum[1];
}

// ---------------- driver --------------------------------------------------------------------
extern "C" void kernel_launch(void* const* d_in, const int* in_sizes, int n_in,
                              void* d_out, int out_size, void* d_ws, size_t ws_size,
                              hipStream_t stream) {
    const float* X      = (const float*)d_in[0];
    const float* adj    = (const float*)d_in[1];
    const float* W0     = (const float*)d_in[2];
    const float* b0     = (const float*)d_in[3];
    const float* W1     = (const float*)d_in[4];
    const float* b1     = (const float*)d_in[5];
    const float* W2     = (const float*)d_in[6];
    const float* b2     = (const float*)d_in[7];
    const float* attn_W = (const float*)d_in[8];
    const float* a1     = (const float*)d_in[9];
    const float* a2     = (const float*)d_in[10];
    const float* dW0    = (const float*)d_in[11];
    const float* db0    = (const float*)d_in[12];
    const float* dW1    = (const float*)d_in[13];
    const float* db1    = (const float*)d_in[14];
    const float* dW2    = (const float*)d_in[15];
    const float* db2    = (const float*)d_in[16];

    float* out  = (float*)d_out;
    float* Hout = out + 1;                       // 4B-aligned only -> scalar stores
    float* Xr   = out + 1 + (size_t)NN * 128;    // 4B-aligned only -> scalar stores

    char* w = (char*)d_ws;
    int*   ell   = (int*)w;   w += (size_t)NN * ELL_W * 4;   // 4 MiB
    int*   cnt   = (int*)w;   w += (size_t)NN * 4;
    float* deg   = (float*)w; w += (size_t)NN * 4;
    float* f1    = (float*)w; w += (size_t)NN * 4;
    float* f2    = (float*)w; w += (size_t)NN * 4;
    float* accum = (float*)w; w += 256;
    float* bufA  = (float*)w; w += (size_t)NN * 512 * 4;     // 16 MiB
    float* bufB  = (float*)w; w += (size_t)NN * 512 * 4;     // 16 MiB
    float* bufC  = (float*)w; w += (size_t)NN * 256 * 4;     // 8 MiB
    float* bufH  = (float*)w; w += (size_t)NN * 128 * 4;     // 4 MiB (aligned copy of H)

    build_ell_kernel<<<dim3(NN / 4), dim3(256), 0, stream>>>(adj, ell, cnt, deg);
    zero_accum_kernel<<<1, 1, 0, stream>>>(accum);

    // 1. XW0 = X @ W0   (8192x1024x512) — 128x64 tile, 512 blocks (2/CU)
    gemm_kernel<8, 4, 0, 0, 0><<<dim3(8, 64), 256, 0, stream>>>(X, W0, nullptr, bufA, NN, 1024, 512, nullptr, nullptr);
    // 2. h0 = lrelu(adj@XW0 + b0)
    spmm_kernel<512><<<NN / 2, 256, 0, stream>>>(bufA, ell, cnt, b0, bufB, nullptr);
    // 3. T1 = h0 @ W1   (8192x512x256) — 64x64 tile, 512 blocks
    gemm_kernel<4, 4, 0, 0, 0><<<dim3(4, 128), 256, 0, stream>>>(bufB, W1, nullptr, bufC, NN, 512, 256, nullptr, nullptr);
    // 4. h1 = lrelu(adj@T1 + b1)
    spmm_kernel<256><<<NN / 4, 256, 0, stream>>>(bufC, ell, cnt, b1, bufA, nullptr);
    // 5. seq_fts = h1 @ attn_W^T   (8192x256x256, NT) — 64x64 tile, 512 blocks
    gemm_kernel<4, 4, 1, 0, 0><<<dim3(4, 128), 256, 0, stream>>>(bufA, attn_W, nullptr, bufB, NN, 256, 256, nullptr, nullptr);
    // 6. f1, f2
    f12_kernel<<<NN / 4, 256, 0, stream>>>(bufB, a1, a2, f1, f2);
    // 7. h2 = lrelu(softmax_nb(lrelu(f1+f2)) @ seq_fts)
    attn_kernel<<<NN / 4, 256, 0, stream>>>(bufB, ell, cnt, f1, f2, bufC);
    // 8. T2 = h2 @ W2   (8192x256x128) — 64x64 tile, 256 blocks (N too small for more)
    gemm_kernel<4, 4, 0, 0, 0><<<dim3(2, 128), 256, 0, stream>>>(bufC, W2, nullptr, bufA, NN, 256, 128, nullptr, nullptr);
    // 9. H = lrelu(adj@T2 + b2) -> aligned bufH + d_out H region
    spmm_kernel<128><<<NN / 8, 256, 0, stream>>>(bufA, ell, cnt, b2, bufH, Hout);
    // 10. Xr0 = sigmoid(H @ dW0 + db0)   (8192x128x256) — 64x64 tile, 512 blocks
    gemm_kernel<4, 4, 0, 1, 0><<<dim3(4, 128), 256, 0, stream>>>(bufH, dW0, db0, bufA, NN, 128, 256, nullptr, nullptr);
    // 11. Xr1 = sigmoid(Xr0 @ dW1 + db1) (8192x256x512) — 128x64 tile, 512 blocks
    gemm_kernel<8, 4, 0, 1, 0><<<dim3(8, 64), 256, 0, stream>>>(bufA, dW1, db1, bufB, NN, 256, 512, nullptr, nullptr);
    // 12. Xr = sigmoid(Xr1 @ dW2 + db2)  (8192x512x1024) — 1024 blocks, FUSED loss_res
    gemm_kernel<8, 4, 0, 1, 1><<<dim3(16, 64), 256, 0, stream>>>(bufB, dW2, db2, Xr, NN, 512, 1024, X, accum);
    // 13. loss_emb + finalize
    loss_emb_kernel<<<NN, 128, 0, stream>>>(bufH, ell, cnt, deg, accum);
    finalize_kernel<<<1, 1, 0, stream>>>(accum, out);
}

// Round 5
// 967.727 us; speedup vs baseline: 1.1600x; 1.0775x over previous
//
#include <hip/hip_runtime.h>
#include <math.h>

#define NN 8192
#define ELL_W 128

typedef __attribute__((ext_vector_type(8))) short bf16x8;
typedef __attribute__((ext_vector_type(4))) float f32x4;

__device__ __forceinline__ float lrelu(float x) { return x > 0.f ? x : 0.01f * x; }

__device__ __forceinline__ unsigned short f2bf(float f) {            // RNE fp32->bf16
    unsigned u = __float_as_uint(f);
    return (unsigned short)((u + 0x7FFFu + ((u >> 16) & 1u)) >> 16);
}
__device__ __forceinline__ float bf2f(unsigned short h) { return __uint_as_float(((unsigned)h) << 16); }
__device__ __forceinline__ void split3(float v, unsigned short& h0, unsigned short& h1, unsigned short& h2) {
    h0 = f2bf(v); float r = v - bf2f(h0);
    h1 = f2bf(r); h2 = f2bf(r - bf2f(h1));
}

// ---------------- ELL build ----------------------------------------------------------------
__global__ void build_ell_kernel(const float* __restrict__ adj, int* __restrict__ ell,
                                 int* __restrict__ cnt, float* __restrict__ deg) {
    const int row  = blockIdx.x * 4 + (threadIdx.x >> 6);
    const int lane = threadIdx.x & 63;
    const float4* arow = (const float4*)(adj + (size_t)row * NN);
    const unsigned long long lmask = (1ull << lane) - 1ull;
    int count = 0;
    for (int c0 = 0; c0 < NN; c0 += 256) {
        const float4 v = arow[(c0 >> 2) + lane];
        const int col = c0 + lane * 4;
        float f[4] = {v.x, v.y, v.z, v.w};
        #pragma unroll
        for (int q = 0; q < 4; ++q) {
            unsigned long long m = __ballot(f[q] > 0.f);
            if (f[q] > 0.f) {
                int pos = count + __popcll(m & lmask);
                if (pos < ELL_W) ell[row * ELL_W + pos] = col + q;
            }
            count += __popcll(m);
        }
    }
    if (lane == 0) {
        cnt[row] = count < ELL_W ? count : ELL_W;
        deg[row] = (float)count;
    }
}

__global__ void zero_accum_kernel(float* accum) { accum[0] = 0.f; accum[1] = 0.f; }

// ---------------- split kernels ------------------------------------------------------------
// X (row-major [M][K]) -> 3 bf16 planes, same layout. 4 elems/thread.
__global__ void splitX_kernel(const float* __restrict__ X, unsigned short* __restrict__ P0,
                              unsigned short* __restrict__ P1, unsigned short* __restrict__ P2,
                              int n4) {
    int i = blockIdx.x * 256 + threadIdx.x;
    if (i >= n4) return;
    const float4 v = ((const float4*)X)[i];
    ushort4 a, b, c;
    split3(v.x, a.x, b.x, c.x); split3(v.y, a.y, b.y, c.y);
    split3(v.z, a.z, b.z, c.z); split3(v.w, a.w, b.w, c.w);
    ((ushort4*)P0)[i] = a; ((ushort4*)P1)[i] = b; ((ushort4*)P2)[i] = c;
}

// W ([K][N] row-major) -> transposed planes [N][K] bf16 (coalesced writes along K).
__global__ void splitWT_kernel(const float* __restrict__ W, unsigned short* __restrict__ P0,
                               unsigned short* __restrict__ P1, unsigned short* __restrict__ P2,
                               int K, int N) {
    int idx = blockIdx.x * 256 + threadIdx.x;
    if (idx >= K * N) return;
    int n = idx / K, k = idx % K;
    unsigned short h0, h1, h2;
    split3(W[(size_t)k * N + n], h0, h1, h2);
    P0[idx] = h0; P1[idx] = h1; P2[idx] = h2;
}

// ---------------- bf16x3-split MFMA GEMM ---------------------------------------------------
// C = act(A@B^T(+bias)) in fp32-grade accuracy via 6 bf16 MFMA products.
// A planes: [M][K] bf16; B planes: [N][K] bf16. Tile 128x64, BK=32, 256 thr (4 waves, 2x2,
// wave tile 64x32). LDS rows padded to 40 ushorts (80B) -> ~2-way bank conflicts.
// ACT: 1 = sigmoid(x+bias). OUT: 0 = f32 C; 1 = split planes C0..C2; 2 = f32 C + fused loss_res.
template <int ACT, int OUT>
__launch_bounds__(256)
__global__ void mfma_gemm_kernel(const unsigned short* __restrict__ A0, const unsigned short* __restrict__ A1,
                                 const unsigned short* __restrict__ A2,
                                 const unsigned short* __restrict__ B0, const unsigned short* __restrict__ B1,
                                 const unsigned short* __restrict__ B2,
                                 const float* __restrict__ bias, int M, int K, int N,
                                 float* __restrict__ Cf,
                                 unsigned short* __restrict__ C0, unsigned short* __restrict__ C1,
                                 unsigned short* __restrict__ C2,
                                 const float* __restrict__ Xref, float* __restrict__ accum) {
    __shared__ __align__(16) unsigned short Al[3][128][40];
    __shared__ __align__(16) unsigned short Bl[3][64][40];
    __shared__ float sred[256];
    const int tid = threadIdx.x;
    const int bm = blockIdx.y * 128, bn = blockIdx.x * 64;
    const int lane = tid & 63;
    const int wr = ((tid >> 6) >> 1) * 64;        // wave row origin (0/64)
    const int wc = ((tid >> 6) & 1) * 32;         // wave col origin (0/32)
    const int lr = lane & 15;                     // A-row / B-col within fragment
    const int lk = (lane >> 4) * 8;               // k-chunk
    f32x4 acc[4][2];
    #pragma unroll
    for (int i = 0; i < 4; ++i)
        #pragma unroll
        for (int j = 0; j < 2; ++j) acc[i][j] = (f32x4){0.f, 0.f, 0.f, 0.f};
    const unsigned short* Ap[3] = {A0, A1, A2};
    const unsigned short* Bp[3] = {B0, B1, B2};

    for (int k0 = 0; k0 < K; k0 += 32) {
        #pragma unroll
        for (int p = 0; p < 3; ++p) {
            #pragma unroll
            for (int e = 0; e < 2; ++e) {          // A: 128 rows x 4 chunks of 8 bf16
                int idx = tid + e * 256;
                int r = idx >> 2, ch = idx & 3;
                const uint4 v = *(const uint4*)(Ap[p] + (size_t)(bm + r) * K + k0 + ch * 8);
                *(uint4*)&Al[p][r][ch * 8] = v;
            }
            {                                      // B: 64 rows x 4 chunks
                int r = tid >> 2, ch = tid & 3;
                const uint4 v = *(const uint4*)(Bp[p] + (size_t)(bn + r) * K + k0 + ch * 8);
                *(uint4*)&Bl[p][r][ch * 8] = v;
            }
        }
        __syncthreads();
        bf16x8 af[3][4], bfr[3][2];
        #pragma unroll
        for (int p = 0; p < 3; ++p) {
            #pragma unroll
            for (int mi = 0; mi < 4; ++mi) af[p][mi] = *(const bf16x8*)&Al[p][wr + mi * 16 + lr][lk];
            #pragma unroll
            for (int ni = 0; ni < 2; ++ni) bfr[p][ni] = *(const bf16x8*)&Bl[p][wc + ni * 16 + lr][lk];
        }
        #pragma unroll
        for (int mi = 0; mi < 4; ++mi)
            #pragma unroll
            for (int ni = 0; ni < 2; ++ni) {
                f32x4 c = acc[mi][ni];
                c = __builtin_amdgcn_mfma_f32_16x16x32_bf16(af[0][mi], bfr[0][ni], c, 0, 0, 0);
                c = __builtin_amdgcn_mfma_f32_16x16x32_bf16(af[0][mi], bfr[1][ni], c, 0, 0, 0);
                c = __builtin_amdgcn_mfma_f32_16x16x32_bf16(af[1][mi], bfr[0][ni], c, 0, 0, 0);
                c = __builtin_amdgcn_mfma_f32_16x16x32_bf16(af[1][mi], bfr[1][ni], c, 0, 0, 0);
                c = __builtin_amdgcn_mfma_f32_16x16x32_bf16(af[0][mi], bfr[2][ni], c, 0, 0, 0);
                c = __builtin_amdgcn_mfma_f32_16x16x32_bf16(af[2][mi], bfr[0][ni], c, 0, 0, 0);
                acc[mi][ni] = c;
            }
        __syncthreads();
    }
    float local = 0.f;
    #pragma unroll
    for (int mi = 0; mi < 4; ++mi)
        #pragma unroll
        for (int ni = 0; ni < 2; ++ni) {
            const int colg = bn + wc + ni * 16 + lr;
            #pragma unroll
            for (int r = 0; r < 4; ++r) {
                const int rowg = bm + wr + mi * 16 + (lane >> 4) * 4 + r;
                float v = acc[mi][ni][r];
                if (ACT) { v += bias[colg]; v = 1.f / (1.f + __expf(-v)); }
                const size_t o = (size_t)rowg * N + colg;
                if (OUT == 0) Cf[o] = v;
                else if (OUT == 1) {
                    unsigned short h0, h1, h2; split3(v, h0, h1, h2);
                    C0[o] = h0; C1[o] = h1; C2[o] = h2;
                } else {
                    Cf[o] = v;
                    float x = Xref[o];
                    float d = (v - x) * fmaf(x, 24.f, 1.f);
                    local = fmaf(d, d, local);
                }
            }
        }
    if (OUT == 2) {
        sred[tid] = local; __syncthreads();
        for (int s = 128; s; s >>= 1) { if (tid < s) sred[tid] += sred[tid + s]; __syncthreads(); }
        if (tid == 0) atomicAdd(accum, sred[0]);
    }
}

// ---------------- fp32 GEMM (small layers) -------------------------------------------------
// MODE: 0 = plain f32 store; 2 = sigmoid(x+bias) then bf16x3 split planes (no f32 out).
template <int PM, int PN, int BT, int MODE>
__global__ void gemm_kernel(const float* __restrict__ A, const float* __restrict__ B,
                            const float* __restrict__ bias, float* __restrict__ C,
                            unsigned short* __restrict__ P0, unsigned short* __restrict__ P1,
                            unsigned short* __restrict__ P2, int M, int K, int N) {
    constexpr int BM = PM * 16;
    constexpr int BN = PN * 16;
    __shared__ __align__(16) float As[16][BM + 4];
    __shared__ __align__(16) float Bs[16][BN + 4];
    const int tid = threadIdx.x;
    const int tx = tid & 15, ty = tid >> 4;
    const int bm = blockIdx.y * BM;
    const int bn = blockIdx.x * BN;
    float acc[PM][PN] = {};
    for (int k0 = 0; k0 < K; k0 += 16) {
        #pragma unroll
        for (int e = 0; e < BM / 64; ++e) {
            int idx = tid + e * 256;
            int m = idx >> 2, q = idx & 3;
            const float4 av = *(const float4*)(A + (size_t)(bm + m) * K + k0 + q * 4);
            As[q * 4 + 0][m] = av.x; As[q * 4 + 1][m] = av.y;
            As[q * 4 + 2][m] = av.z; As[q * 4 + 3][m] = av.w;
        }
        if (BT == 0) {
            #pragma unroll
            for (int e = 0; e < BN / 64; ++e) {
                int idx = tid + e * 256;
                int kk = idx / (BN / 4), nq = idx % (BN / 4);
                const float4 bv = *(const float4*)(B + (size_t)(k0 + kk) * N + bn + nq * 4);
                *(float4*)&Bs[kk][nq * 4] = bv;
            }
        } else {
            #pragma unroll
            for (int e = 0; e < BN / 64; ++e) {
                int idx = tid + e * 256;
                int n = idx >> 2, q = idx & 3;
                const float4 bv = *(const float4*)(B + (size_t)(bn + n) * K + k0 + q * 4);
                Bs[q * 4 + 0][n] = bv.x; Bs[q * 4 + 1][n] = bv.y;
                Bs[q * 4 + 2][n] = bv.z; Bs[q * 4 + 3][n] = bv.w;
            }
        }
        __syncthreads();
        #pragma unroll
        for (int kk = 0; kk < 16; ++kk) {
            float a[PM], b[PN];
            #pragma unroll
            for (int e = 0; e < PM / 4; ++e)
                *(float4*)&a[e * 4] = *(const float4*)&As[kk][ty * PM + e * 4];
            #pragma unroll
            for (int e = 0; e < PN / 4; ++e)
                *(float4*)&b[e * 4] = *(const float4*)&Bs[kk][tx * PN + e * 4];
            #pragma unroll
            for (int i = 0; i < PM; ++i)
                #pragma unroll
                for (int j = 0; j < PN; ++j)
                    acc[i][j] = fmaf(a[i], b[j], acc[i][j]);
        }
        __syncthreads();
    }
    #pragma unroll
    for (int i = 0; i < PM; ++i) {
        size_t m = (size_t)(bm + ty * PM + i);
        if (MODE == 0) {
            #pragma unroll
            for (int j = 0; j < PN; ++j)
                C[m * N + bn + tx * PN + j] = acc[i][j];
        } else {                                   // sigmoid + split (PN==4)
            ushort4 h0, h1, h2;
            unsigned short* p0 = (unsigned short*)&h0;
            unsigned short* p1 = (unsigned short*)&h1;
            unsigned short* p2 = (unsigned short*)&h2;
            #pragma unroll
            for (int j = 0; j < PN; ++j) {
                int n = bn + tx * PN + j;
                float v = acc[i][j] + bias[n];
                v = 1.f / (1.f + __expf(-v));
                split3(v, p0[j], p1[j], p2[j]);
            }
            size_t o = m * N + bn + tx * PN;
            *(ushort4*)(P0 + o) = h0; *(ushort4*)(P1 + o) = h1; *(ushort4*)(P2 + o) = h2;
        }
    }
}

// ---------------- adj @ M gather-sum + bias + lrelu -----------------------------------------
template <int C>
__global__ void spmm_kernel(const float* __restrict__ M, const int* __restrict__ ell,
                            const int* __restrict__ cnt, const float* __restrict__ bias,
                            float* __restrict__ out, float* __restrict__ out2) {
    constexpr int TPR = C / 4;
    constexpr int RPB = 256 / TPR;
    const int rid = threadIdx.x / TPR;
    const int c4  = threadIdx.x % TPR;
    const int row = blockIdx.x * RPB + rid;
    __shared__ int nb_s[RPB][ELL_W];
    const int n = cnt[row];
    for (int t = c4; t < n; t += TPR) nb_s[rid][t] = ell[row * ELL_W + t];
    __syncthreads();
    float4 acc = {0.f, 0.f, 0.f, 0.f};
    for (int t = 0; t < n; ++t) {
        const float4 v = *(const float4*)(M + (size_t)nb_s[rid][t] * C + c4 * 4);
        acc.x += v.x; acc.y += v.y; acc.z += v.z; acc.w += v.w;
    }
    const float4 bv = *(const float4*)(bias + c4 * 4);
    float4 r;
    r.x = lrelu(acc.x + bv.x); r.y = lrelu(acc.y + bv.y);
    r.z = lrelu(acc.z + bv.z); r.w = lrelu(acc.w + bv.w);
    *(float4*)(out + (size_t)row * C + c4 * 4) = r;
    if (out2) {
        size_t o = (size_t)row * C + c4 * 4;
        out2[o] = r.x; out2[o + 1] = r.y; out2[o + 2] = r.z; out2[o + 3] = r.w;
    }
}

// ---------------- f1/f2, attention, losses (unchanged from R4) ------------------------------
__global__ void f12_kernel(const float* __restrict__ seq, const float* __restrict__ a1,
                           const float* __restrict__ a2, float* __restrict__ f1,
                           float* __restrict__ f2) {
    const int row = blockIdx.x * 4 + (threadIdx.x >> 6);
    const int lane = threadIdx.x & 63;
    const float4 v  = *(const float4*)(seq + (size_t)row * 256 + lane * 4);
    const float4 w1 = *(const float4*)(a1 + lane * 4);
    const float4 w2 = *(const float4*)(a2 + lane * 4);
    float s1 = v.x * w1.x + v.y * w1.y + v.z * w1.z + v.w * w1.w;
    float s2 = v.x * w2.x + v.y * w2.y + v.z * w2.z + v.w * w2.w;
    #pragma unroll
    for (int o = 32; o; o >>= 1) { s1 += __shfl_xor(s1, o); s2 += __shfl_xor(s2, o); }
    if (lane == 0) { f1[row] = s1; f2[row] = s2; }
}

__global__ void attn_kernel(const float* __restrict__ seq, const int* __restrict__ ell,
                            const int* __restrict__ cnt, const float* __restrict__ f1,
                            const float* __restrict__ f2, float* __restrict__ out) {
    const int wid = threadIdx.x >> 6, lane = threadIdx.x & 63;
    const int row = blockIdx.x * 4 + wid;
    __shared__ int   nb_s[4][ELL_W];
    __shared__ float cf_s[4][ELL_W];
    const int n = cnt[row];
    const float f1r = f1[row];
    float m = -3.0e38f;
    for (int t = lane; t < n; t += 64) {
        int j = ell[row * ELL_W + t];
        nb_s[wid][t] = j;
        float v = lrelu(f1r + f2[j]);
        cf_s[wid][t] = v;
        m = fmaxf(m, v);
    }
    #pragma unroll
    for (int o = 32; o; o >>= 1) m = fmaxf(m, __shfl_xor(m, o));
    __syncthreads();
    float s = 0.f;
    for (int t = lane; t < n; t += 64) {
        float e = __expf(cf_s[wid][t] - m);
        cf_s[wid][t] = e;
        s += e;
    }
    #pragma unroll
    for (int o = 32; o; o >>= 1) s += __shfl_xor(s, o);
    const float inv = 1.f / s;
    __syncthreads();
    float4 acc = {0.f, 0.f, 0.f, 0.f};
    for (int t = 0; t < n; ++t) {
        const float c = cf_s[wid][t];
        const float4 v = *(const float4*)(seq + (size_t)nb_s[wid][t] * 256 + lane * 4);
        acc.x = fmaf(c, v.x, acc.x); acc.y = fmaf(c, v.y, acc.y);
        acc.z = fmaf(c, v.z, acc.z); acc.w = fmaf(c, v.w, acc.w);
    }
    float4 r;
    r.x = lrelu(acc.x * inv); r.y = lrelu(acc.y * inv);
    r.z = lrelu(acc.z * inv); r.w = lrelu(acc.w * inv);
    *(float4*)(out + (size_t)row * 256 + lane * 4) = r;
}

__global__ void loss_emb_kernel(const float* __restrict__ H, const int* __restrict__ ell,
                                const int* __restrict__ cnt, const float* __restrict__ deg,
                                float* __restrict__ accum) {
    const int row = blockIdx.x, tid = threadIdx.x;
    __shared__ int nb[ELL_W];
    __shared__ float sred[128];
    const int n = cnt[row];
    if (tid < n) nb[tid] = ell[row * ELL_W + tid];
    __syncthreads();
    float hv = H[(size_t)row * 128 + tid];
    float g = 0.f;
    for (int t = 0; t < n; ++t) g += H[(size_t)nb[t] * 128 + tid];
    float lh = deg[row] * hv - g;
    sred[tid] = hv * lh; __syncthreads();
    for (int s = 64; s; s >>= 1) { if (tid < s) sred[tid] += sred[tid + s]; __syncthreads(); }
    if (tid == 0) atomicAdd(accum + 1, sred[0]);
}

__global__ void finalize_kernel(const float* __restrict__ accum, float* __restrict__ out) {
    out[0] = 100.f * accum[0] + 2.f * accum[1];
}

// ---------------- driver --------------------------------------------------------------------
extern "C" void kernel_launch(void* const* d_in, const int* in_sizes, int n_in,
                              void* d_out, int out_size, void* d_ws, size_t ws_size,
                              hipStream_t stream) {
    const float* X      = (const float*)d_in[0];
    const float* adj    = (const float*)d_in[1];
    const float* W0     = (const float*)d_in[2];
    const float* b0     = (const float*)d_in[3];
    const float* W1     = (const float*)d_in[4];
    const float* b1     = (const float*)d_in[5];
    const float* W2     = (const float*)d_in[6];
    const float* b2     = (const float*)d_in[7];
    const float* attn_W = (const float*)d_in[8];
    const float* a1     = (const float*)d_in[9];
    const float* a2     = (const float*)d_in[10];
    const float* dW0    = (const float*)d_in[11];
    const float* db0    = (const float*)d_in[12];
    const float* dW1    = (const float*)d_in[13];
    const float* db1    = (const float*)d_in[14];
    const float* dW2    = (const float*)d_in[15];
    const float* db2    = (const float*)d_in[16];

    float* out  = (float*)d_out;
    float* Hout = out + 1;
    float* Xr   = out + 1 + (size_t)NN * 128;

    char* w = (char*)d_ws;
    int*   ell   = (int*)w;   w += (size_t)NN * ELL_W * 4;
    int*   cnt   = (int*)w;   w += (size_t)NN * 4;
    float* deg   = (float*)w; w += (size_t)NN * 4;
    float* f1    = (float*)w; w += (size_t)NN * 4;
    float* f2    = (float*)w; w += (size_t)NN * 4;
    float* accum = (float*)w; w += 256;
    float* bufA  = (float*)w; w += (size_t)NN * 512 * 4;      // 16 MiB
    float* bufB  = (float*)w; w += (size_t)NN * 512 * 4;      // 16 MiB
    float* bufC  = (float*)w; w += (size_t)NN * 256 * 4;      // 8 MiB
    float* bufH  = (float*)w; w += (size_t)NN * 128 * 4;      // 4 MiB
    unsigned short* XP[3];  for (int i = 0; i < 3; ++i) { XP[i]  = (unsigned short*)w; w += (size_t)NN * 1024 * 2; }
    unsigned short* W0T[3]; for (int i = 0; i < 3; ++i) { W0T[i] = (unsigned short*)w; w += (size_t)512 * 1024 * 2; }
    unsigned short* W1T[3]; for (int i = 0; i < 3; ++i) { W1T[i] = (unsigned short*)w; w += (size_t)512 * 256 * 2; }
    unsigned short* W2T[3]; for (int i = 0; i < 3; ++i) { W2T[i] = (unsigned short*)w; w += (size_t)1024 * 512 * 2; }
    unsigned short* R0P[3]; for (int i = 0; i < 3; ++i) { R0P[i] = (unsigned short*)w; w += (size_t)NN * 256 * 2; }
    unsigned short* R1P[3]; for (int i = 0; i < 3; ++i) { R1P[i] = (unsigned short*)w; w += (size_t)NN * 512 * 2; }

    build_ell_kernel<<<dim3(NN / 4), dim3(256), 0, stream>>>(adj, ell, cnt, deg);
    zero_accum_kernel<<<1, 1, 0, stream>>>(accum);

    // splits for MFMA path
    splitX_kernel<<<NN * 1024 / 4 / 256, 256, 0, stream>>>(X, XP[0], XP[1], XP[2], NN * 1024 / 4);
    splitWT_kernel<<<1024 * 512 / 256, 256, 0, stream>>>(W0, W0T[0], W0T[1], W0T[2], 1024, 512);
    splitWT_kernel<<<256 * 512 / 256, 256, 0, stream>>>(dW1, W1T[0], W1T[1], W1T[2], 256, 512);
    splitWT_kernel<<<512 * 1024 / 256, 256, 0, stream>>>(dW2, W2T[0], W2T[1], W2T[2], 512, 1024);

    // 1. XW0 = X @ W0 (8192x1024x512) — MFMA bf16x3
    mfma_gemm_kernel<0, 0><<<dim3(512 / 64, NN / 128), 256, 0, stream>>>(
        XP[0], XP[1], XP[2], W0T[0], W0T[1], W0T[2], nullptr, NN, 1024, 512,
        bufA, nullptr, nullptr, nullptr, nullptr, nullptr);
    // 2. h0 = lrelu(adj@XW0 + b0)
    spmm_kernel<512><<<NN / 2, 256, 0, stream>>>(bufA, ell, cnt, b0, bufB, nullptr);
    // 3. T1 = h0 @ W1 (fp32)
    gemm_kernel<4, 4, 0, 0><<<dim3(4, 128), 256, 0, stream>>>(bufB, W1, nullptr, bufC, nullptr, nullptr, nullptr, NN, 512, 256);
    // 4. h1 = lrelu(adj@T1 + b1)
    spmm_kernel<256><<<NN / 4, 256, 0, stream>>>(bufC, ell, cnt, b1, bufA, nullptr);
    // 5. seq_fts = h1 @ attn_W^T (fp32, NT)
    gemm_kernel<4, 4, 1, 0><<<dim3(4, 128), 256, 0, stream>>>(bufA, attn_W, nullptr, bufB, nullptr, nullptr, nullptr, NN, 256, 256);
    // 6. f1, f2
    f12_kernel<<<NN / 4, 256, 0, stream>>>(bufB, a1, a2, f1, f2);
    // 7. h2 = attention
    attn_kernel<<<NN / 4, 256, 0, stream>>>(bufB, ell, cnt, f1, f2, bufC);
    // 8. T2 = h2 @ W2 (fp32)
    gemm_kernel<4, 4, 0, 0><<<dim3(2, 128), 256, 0, stream>>>(bufC, W2, nullptr, bufA, nullptr, nullptr, nullptr, NN, 256, 128);
    // 9. H = lrelu(adj@T2 + b2)
    spmm_kernel<128><<<NN / 8, 256, 0, stream>>>(bufA, ell, cnt, b2, bufH, Hout);
    // 10. Xr0 = sigmoid(H @ dW0 + db0) (fp32 compute, split-plane output)
    gemm_kernel<4, 4, 0, 2><<<dim3(4, 128), 256, 0, stream>>>(bufH, dW0, db0, nullptr, R0P[0], R0P[1], R0P[2], NN, 128, 256);
    // 11. Xr1 = sigmoid(Xr0 @ dW1 + db1) (MFMA, split-plane output)
    mfma_gemm_kernel<1, 1><<<dim3(512 / 64, NN / 128), 256, 0, stream>>>(
        R0P[0], R0P[1], R0P[2], W1T[0], W1T[1], W1T[2], db1, NN, 256, 512,
        nullptr, R1P[0], R1P[1], R1P[2], nullptr, nullptr);
    // 12. Xr = sigmoid(Xr1 @ dW2 + db2) (MFMA, f32 out + fused loss_res)
    mfma_gemm_kernel<1, 2><<<dim3(1024 / 64, NN / 128), 256, 0, stream>>>(
        R1P[0], R1P[1], R1P[2], W2T[0], W2T[1], W2T[2], db2, NN, 512, 1024,
        Xr, nullptr, nullptr, nullptr, X, accum);
    // 13. loss_emb + finalize
    loss_emb_kernel<<<NN, 128, 0, stream>>>(bufH, ell, cnt, deg, accum);
    finalize_kernel<<<1, 1, 0, stream>>>(accum, out);
}

// Round 6
// 929.406 us; speedup vs baseline: 1.2078x; 1.0412x over previous
//
#include <hip/hip_runtime.h>
#include <math.h>

#define NN 8192
#define ELL_W 128

typedef __attribute__((ext_vector_type(8))) short bf16x8;
typedef __attribute__((ext_vector_type(4))) float f32x4;

__device__ __forceinline__ float lrelu(float x) { return x > 0.f ? x : 0.01f * x; }
__device__ __forceinline__ unsigned short f2bf(float f) {            // RNE fp32->bf16
    unsigned u = __float_as_uint(f);
    return (unsigned short)((u + 0x7FFFu + ((u >> 16) & 1u)) >> 16);
}
__device__ __forceinline__ float bf2f(unsigned short h) { return __uint_as_float(((unsigned)h) << 16); }
__device__ __forceinline__ void split3(float v, unsigned short& h0, unsigned short& h1, unsigned short& h2) {
    h0 = f2bf(v); float r = v - bf2f(h0);
    h1 = f2bf(r); h2 = f2bf(r - bf2f(h1));
}

// async global->LDS, 16B per lane; LDS dest = wave-uniform base + lane*16
__device__ __forceinline__ void gload_lds16(const unsigned short* g, unsigned short* l) {
    __builtin_amdgcn_global_load_lds((const __attribute__((address_space(1))) unsigned int*)g,
                                     (__attribute__((address_space(3))) unsigned int*)l, 16, 0, 0);
}

// ---- MFMA plane layout helpers -------------------------------------------------------------
// A-plane (MxK): [M/128][K/32] tiles, tile = [r:128][pc:4][e:8] ushorts, pc = (c+(r>>1))&3.
// B-plane (NxK): [N/64][K/32] tiles, tile = [r:64][pc:4][e:8], same swizzle. Linear LDS stage,
// ds_read_b128 fragments land 2-way bank-aliased (free).
__device__ __forceinline__ size_t a_plane_off(int rowg, int kg, int K) {
    int rr = rowg & 127, kk = kg & 31;
    int pc = (((kk >> 3) + (rr >> 1)) & 3);
    return ((size_t)(rowg >> 7) * (K >> 5) + (kg >> 5)) * 4096 + rr * 32 + pc * 8 + (kk & 7);
}

// ---------------- ELL build ----------------------------------------------------------------
__global__ void build_ell_kernel(const float* __restrict__ adj, int* __restrict__ ell,
                                 int* __restrict__ cnt, float* __restrict__ deg) {
    const int row  = blockIdx.x * 4 + (threadIdx.x >> 6);
    const int lane = threadIdx.x & 63;
    const float4* arow = (const float4*)(adj + (size_t)row * NN);
    const unsigned long long lmask = (1ull << lane) - 1ull;
    int count = 0;
    for (int c0 = 0; c0 < NN; c0 += 256) {
        const float4 v = arow[(c0 >> 2) + lane];
        const int col = c0 + lane * 4;
        float f[4] = {v.x, v.y, v.z, v.w};
        #pragma unroll
        for (int q = 0; q < 4; ++q) {
            unsigned long long m = __ballot(f[q] > 0.f);
            if (f[q] > 0.f) {
                int pos = count + __popcll(m & lmask);
                if (pos < ELL_W) ell[row * ELL_W + pos] = col + q;
            }
            count += __popcll(m);
        }
    }
    if (lane == 0) {
        cnt[row] = count < ELL_W ? count : ELL_W;
        deg[row] = (float)count;
    }
}

__global__ void zero_accum_kernel(float* accum) { accum[0] = 0.f; accum[1] = 0.f; }

// ---------------- split kernels (emit tiled-swizzled planes) --------------------------------
// A-source [M][K] row-major -> A-planes. One thread per 16B chunk.
__global__ void splitA_kernel(const float* __restrict__ src, unsigned short* __restrict__ P0,
                              unsigned short* __restrict__ P1, unsigned short* __restrict__ P2,
                              int K, int nchunks) {
    int g = blockIdx.x * 256 + threadIdx.x;
    if (g >= nchunks) return;
    const int KT = K >> 5;
    int t = g >> 9, w = g & 511;                 // 512 chunks per 128x32 tile
    int r = w >> 2, pc = w & 3;
    int c = (pc - (r >> 1)) & 3;
    int tm = t / KT, tk = t % KT;
    const float* s = src + (size_t)(tm * 128 + r) * K + tk * 32 + c * 8;
    const float4 v0 = *(const float4*)s, v1 = *(const float4*)(s + 4);
    float f[8] = {v0.x, v0.y, v0.z, v0.w, v1.x, v1.y, v1.z, v1.w};
    unsigned short a0[8], a1[8], a2[8];
    #pragma unroll
    for (int j = 0; j < 8; ++j) split3(f[j], a0[j], a1[j], a2[j]);
    *(uint4*)(P0 + (size_t)g * 8) = *(uint4*)a0;
    *(uint4*)(P1 + (size_t)g * 8) = *(uint4*)a1;
    *(uint4*)(P2 + (size_t)g * 8) = *(uint4*)a2;
}

// W [K][N] row-major (needs transpose) -> B-planes [N/64][K/32]
__global__ void splitBT_kernel(const float* __restrict__ W, unsigned short* __restrict__ P0,
                               unsigned short* __restrict__ P1, unsigned short* __restrict__ P2,
                               int K, int N, int nchunks) {
    int g = blockIdx.x * 256 + threadIdx.x;
    if (g >= nchunks) return;
    const int KT = K >> 5;
    int t = g >> 8, w = g & 255;                 // 256 chunks per 64x32 tile
    int r = w >> 2, pc = w & 3;
    int c = (pc - (r >> 1)) & 3;
    int tn = t / KT, tk = t % KT;
    const float* s = W + (size_t)(tk * 32 + c * 8) * N + tn * 64 + r;
    unsigned short a0[8], a1[8], a2[8];
    #pragma unroll
    for (int j = 0; j < 8; ++j) split3(s[(size_t)j * N], a0[j], a1[j], a2[j]);
    *(uint4*)(P0 + (size_t)g * 8) = *(uint4*)a0;
    *(uint4*)(P1 + (size_t)g * 8) = *(uint4*)a1;
    *(uint4*)(P2 + (size_t)g * 8) = *(uint4*)a2;
}

// Wrow [N][K] row-major (already B-oriented) -> B-planes
__global__ void splitBR_kernel(const float* __restrict__ W, unsigned short* __restrict__ P0,
                               unsigned short* __restrict__ P1, unsigned short* __restrict__ P2,
                               int K, int nchunks) {
    int g = blockIdx.x * 256 + threadIdx.x;
    if (g >= nchunks) return;
    const int KT = K >> 5;
    int t = g >> 8, w = g & 255;
    int r = w >> 2, pc = w & 3;
    int c = (pc - (r >> 1)) & 3;
    int tn = t / KT, tk = t % KT;
    const float* s = W + (size_t)(tn * 64 + r) * K + tk * 32 + c * 8;
    const float4 v0 = *(const float4*)s, v1 = *(const float4*)(s + 4);
    float f[8] = {v0.x, v0.y, v0.z, v0.w, v1.x, v1.y, v1.z, v1.w};
    unsigned short a0[8], a1[8], a2[8];
    #pragma unroll
    for (int j = 0; j < 8; ++j) split3(f[j], a0[j], a1[j], a2[j]);
    *(uint4*)(P0 + (size_t)g * 8) = *(uint4*)a0;
    *(uint4*)(P1 + (size_t)g * 8) = *(uint4*)a1;
    *(uint4*)(P2 + (size_t)g * 8) = *(uint4*)a2;
}

// ---------------- bf16x3 MFMA GEMM (global_load_lds staging) --------------------------------
// C = act(A@B^T(+bias)). Tile 128x64, BK=32, 4 waves 2x2 (wave 64x32). LDS 36KB single-buffer.
// ACT: 1 = sigmoid(x+bias). OUT: 0 = f32 C; 1 = A-planes of C (K2=N); 2 = f32 C + loss_res.
template <int ACT, int OUT>
__launch_bounds__(256)
__global__ void mfma_gemm_kernel(const unsigned short* __restrict__ A0, const unsigned short* __restrict__ A1,
                                 const unsigned short* __restrict__ A2,
                                 const unsigned short* __restrict__ B0, const unsigned short* __restrict__ B1,
                                 const unsigned short* __restrict__ B2,
                                 const float* __restrict__ bias, int K, int N,
                                 float* __restrict__ Cf,
                                 unsigned short* __restrict__ C0, unsigned short* __restrict__ C1,
                                 unsigned short* __restrict__ C2,
                                 const float* __restrict__ Xref, float* __restrict__ accum) {
    __shared__ __align__(16) unsigned short lds[18432];   // A 3x4096 @0, B 3x2048 @12288
    __shared__ float sred[256];
    const int tid = threadIdx.x, lane = tid & 63, wv = tid >> 6;
    const int KT = K >> 5;
    const int bm = blockIdx.y * 128, bn = blockIdx.x * 64;
    const int wr = (wv >> 1) * 64, wc = (wv & 1) * 32;
    const int lr = lane & 15, cch = lane >> 4;

    const unsigned short* Ap[3] = {A0 + (size_t)blockIdx.y * KT * 4096,
                                   A1 + (size_t)blockIdx.y * KT * 4096,
                                   A2 + (size_t)blockIdx.y * KT * 4096};
    const unsigned short* Bp[3] = {B0 + (size_t)blockIdx.x * KT * 2048,
                                   B1 + (size_t)blockIdx.x * KT * 2048,
                                   B2 + (size_t)blockIdx.x * KT * 2048};
    int offA[4], offB[2];
    #pragma unroll
    for (int mi = 0; mi < 4; ++mi) { int r = wr + mi * 16 + lr; offA[mi] = r * 32 + (((cch + (r >> 1)) & 3) << 3); }
    #pragma unroll
    for (int ni = 0; ni < 2; ++ni) { int r = wc + ni * 16 + lr; offB[ni] = r * 32 + (((cch + (r >> 1)) & 3) << 3); }

    f32x4 acc[4][2];
    #pragma unroll
    for (int i = 0; i < 4; ++i)
        #pragma unroll
        for (int j = 0; j < 2; ++j) acc[i][j] = (f32x4){0.f, 0.f, 0.f, 0.f};

    for (int tk = 0; tk < KT; ++tk) {
        #pragma unroll
        for (int i = 0; i < 6; ++i) {              // A: 24 x 1KB segments over 4 waves
            int s = i * 4 + wv, p = s >> 3, q = s & 7;
            gload_lds16(Ap[p] + (size_t)tk * 4096 + q * 512 + lane * 8, &lds[p * 4096 + q * 512]);
        }
        #pragma unroll
        for (int i = 0; i < 3; ++i) {              // B: 12 x 1KB segments
            int s = i * 4 + wv, p = s >> 2, q = s & 3;
            gload_lds16(Bp[p] + (size_t)tk * 2048 + q * 512 + lane * 8, &lds[12288 + p * 2048 + q * 512]);
        }
        __syncthreads();                           // drains vmcnt -> LDS tile ready
        bf16x8 af[3][4], bfr[3][2];
        #pragma unroll
        for (int p = 0; p < 3; ++p) {
            #pragma unroll
            for (int mi = 0; mi < 4; ++mi) af[p][mi] = *(const bf16x8*)&lds[p * 4096 + offA[mi]];
            #pragma unroll
            for (int ni = 0; ni < 2; ++ni) bfr[p][ni] = *(const bf16x8*)&lds[12288 + p * 2048 + offB[ni]];
        }
        #pragma unroll
        for (int mi = 0; mi < 4; ++mi)
            #pragma unroll
            for (int ni = 0; ni < 2; ++ni) {
                f32x4 c = acc[mi][ni];
                c = __builtin_amdgcn_mfma_f32_16x16x32_bf16(af[0][mi], bfr[0][ni], c, 0, 0, 0);
                c = __builtin_amdgcn_mfma_f32_16x16x32_bf16(af[0][mi], bfr[1][ni], c, 0, 0, 0);
                c = __builtin_amdgcn_mfma_f32_16x16x32_bf16(af[1][mi], bfr[0][ni], c, 0, 0, 0);
                c = __builtin_amdgcn_mfma_f32_16x16x32_bf16(af[1][mi], bfr[1][ni], c, 0, 0, 0);
                c = __builtin_amdgcn_mfma_f32_16x16x32_bf16(af[0][mi], bfr[2][ni], c, 0, 0, 0);
                c = __builtin_amdgcn_mfma_f32_16x16x32_bf16(af[2][mi], bfr[0][ni], c, 0, 0, 0);
                acc[mi][ni] = c;
            }
        __syncthreads();                           // reads done before next overwrite
    }
    float local = 0.f;
    #pragma unroll
    for (int mi = 0; mi < 4; ++mi)
        #pragma unroll
        for (int ni = 0; ni < 2; ++ni) {
            const int colg = bn + wc + ni * 16 + lr;
            #pragma unroll
            for (int r = 0; r < 4; ++r) {
                const int rowg = bm + wr + mi * 16 + cch * 4 + r;
                float v = acc[mi][ni][r];
                if (ACT) { v += bias[colg]; v = 1.f / (1.f + __expf(-v)); }
                if (OUT == 0) {
                    Cf[(size_t)rowg * N + colg] = v;
                } else if (OUT == 1) {             // emit A-planes for next GEMM (K2 = N)
                    size_t po = a_plane_off(rowg, colg, N);
                    unsigned short h0, h1, h2; split3(v, h0, h1, h2);
                    C0[po] = h0; C1[po] = h1; C2[po] = h2;
                } else {
                    const size_t o = (size_t)rowg * N + colg;
                    Cf[o] = v;
                    float x = Xref[o];
                    float d = (v - x) * fmaf(x, 24.f, 1.f);
                    local = fmaf(d, d, local);
                }
            }
        }
    if (OUT == 2) {
        sred[tid] = local; __syncthreads();
        for (int s = 128; s; s >>= 1) { if (tid < s) sred[tid] += sred[tid + s]; __syncthreads(); }
        if (tid == 0) atomicAdd(accum, sred[0]);
    }
}

// ---------------- adj @ M gather-sum + bias + lrelu -----------------------------------------
// OUTF: write f32 out (+ optional scalar out2). OUTP: emit A-planes (K=C) for next MFMA GEMM.
template <int C, int OUTF, int OUTP>
__global__ void spmm_kernel(const float* __restrict__ M_, const int* __restrict__ ell,
                            const int* __restrict__ cnt, const float* __restrict__ bias,
                            float* __restrict__ out, float* __restrict__ out2,
                            unsigned short* __restrict__ P0, unsigned short* __restrict__ P1,
                            unsigned short* __restrict__ P2) {
    constexpr int TPR = C / 4;
    constexpr int RPB = 256 / TPR;
    const int rid = threadIdx.x / TPR;
    const int c4  = threadIdx.x % TPR;
    const int row = blockIdx.x * RPB + rid;
    __shared__ int nb_s[RPB][ELL_W];
    const int n = cnt[row];
    for (int t = c4; t < n; t += TPR) nb_s[rid][t] = ell[row * ELL_W + t];
    __syncthreads();
    float4 acc = {0.f, 0.f, 0.f, 0.f};
    for (int t = 0; t < n; ++t) {
        const float4 v = *(const float4*)(M_ + (size_t)nb_s[rid][t] * C + c4 * 4);
        acc.x += v.x; acc.y += v.y; acc.z += v.z; acc.w += v.w;
    }
    const float4 bv = *(const float4*)(bias + c4 * 4);
    float4 r;
    r.x = lrelu(acc.x + bv.x); r.y = lrelu(acc.y + bv.y);
    r.z = lrelu(acc.z + bv.z); r.w = lrelu(acc.w + bv.w);
    if (OUTF) {
        *(float4*)(out + (size_t)row * C + c4 * 4) = r;
        if (out2) {                                // +4B-misaligned d_out region: scalar
            size_t o = (size_t)row * C + c4 * 4;
            out2[o] = r.x; out2[o + 1] = r.y; out2[o + 2] = r.z; out2[o + 3] = r.w;
        }
    }
    if (OUTP) {
        constexpr int KT = C >> 5;
        int tm = row >> 7, rr = row & 127;
        int tk = c4 >> 3, cc = (c4 >> 1) & 3, h = c4 & 1;
        int pc = (cc + (rr >> 1)) & 3;
        size_t off = ((size_t)tm * KT + tk) * 4096 + rr * 32 + pc * 8 + h * 4;
        ushort4 q0, q1, q2;
        split3(r.x, q0.x, q1.x, q2.x); split3(r.y, q0.y, q1.y, q2.y);
        split3(r.z, q0.z, q1.z, q2.z); split3(r.w, q0.w, q1.w, q2.w);
        *(ushort4*)(P0 + off) = q0; *(ushort4*)(P1 + off) = q1; *(ushort4*)(P2 + off) = q2;
    }
}

// ---------------- f1 = seq@a1, f2 = seq@a2 --------------------------------------------------
__global__ void f12_kernel(const float* __restrict__ seq, const float* __restrict__ a1,
                           const float* __restrict__ a2, float* __restrict__ f1,
                           float* __restrict__ f2) {
    const int row = blockIdx.x * 4 + (threadIdx.x >> 6);
    const int lane = threadIdx.x & 63;
    const float4 v  = *(const float4*)(seq + (size_t)row * 256 + lane * 4);
    const float4 w1 = *(const float4*)(a1 + lane * 4);
    const float4 w2 = *(const float4*)(a2 + lane * 4);
    float s1 = v.x * w1.x + v.y * w1.y + v.z * w1.z + v.w * w1.w;
    float s2 = v.x * w2.x + v.y * w2.y + v.z * w2.z + v.w * w2.w;
    #pragma unroll
    for (int o = 32; o; o >>= 1) { s1 += __shfl_xor(s1, o); s2 += __shfl_xor(s2, o); }
    if (lane == 0) { f1[row] = s1; f2[row] = s2; }
}

// ---------------- sparse GAT: neighbor softmax + weighted gather -> A-planes (K=256) --------
__global__ void attn_kernel(const float* __restrict__ seq, const int* __restrict__ ell,
                            const int* __restrict__ cnt, const float* __restrict__ f1,
                            const float* __restrict__ f2,
                            unsigned short* __restrict__ P0, unsigned short* __restrict__ P1,
                            unsigned short* __restrict__ P2) {
    const int wid = threadIdx.x >> 6, lane = threadIdx.x & 63;
    const int row = blockIdx.x * 4 + wid;
    __shared__ int   nb_s[4][ELL_W];
    __shared__ float cf_s[4][ELL_W];
    const int n = cnt[row];
    const float f1r = f1[row];
    float m = -3.0e38f;
    for (int t = lane; t < n; t += 64) {
        int j = ell[row * ELL_W + t];
        nb_s[wid][t] = j;
        float v = lrelu(f1r + f2[j]);
        cf_s[wid][t] = v;
        m = fmaxf(m, v);
    }
    #pragma unroll
    for (int o = 32; o; o >>= 1) m = fmaxf(m, __shfl_xor(m, o));
    __syncthreads();
    float s = 0.f;
    for (int t = lane; t < n; t += 64) {
        float e = __expf(cf_s[wid][t] - m);
        cf_s[wid][t] = e;
        s += e;
    }
    #pragma unroll
    for (int o = 32; o; o >>= 1) s += __shfl_xor(s, o);
    const float inv = 1.f / s;
    __syncthreads();
    float4 acc = {0.f, 0.f, 0.f, 0.f};
    for (int t = 0; t < n; ++t) {
        const float c = cf_s[wid][t];
        const float4 v = *(const float4*)(seq + (size_t)nb_s[wid][t] * 256 + lane * 4);
        acc.x = fmaf(c, v.x, acc.x); acc.y = fmaf(c, v.y, acc.y);
        acc.z = fmaf(c, v.z, acc.z); acc.w = fmaf(c, v.w, acc.w);
    }
    float4 r;
    r.x = lrelu(acc.x * inv); r.y = lrelu(acc.y * inv);
    r.z = lrelu(acc.z * inv); r.w = lrelu(acc.w * inv);
    // plane write: cols lane*4 .. lane*4+3, K=256
    int tm = row >> 7, rr = row & 127;
    int tk = lane >> 3, cc = (lane >> 1) & 3, h = lane & 1;
    int pc = (cc + (rr >> 1)) & 3;
    size_t off = ((size_t)tm * 8 + tk) * 4096 + rr * 32 + pc * 8 + h * 4;
    ushort4 q0, q1, q2;
    split3(r.x, q0.x, q1.x, q2.x); split3(r.y, q0.y, q1.y, q2.y);
    split3(r.z, q0.z, q1.z, q2.z); split3(r.w, q0.w, q1.w, q2.w);
    *(ushort4*)(P0 + off) = q0; *(ushort4*)(P1 + off) = q1; *(ushort4*)(P2 + off) = q2;
}

// ---------------- loss_emb ------------------------------------------------------------------
__global__ void loss_emb_kernel(const float* __restrict__ H, const int* __restrict__ ell,
                                const int* __restrict__ cnt, const float* __restrict__ deg,
                                float* __restrict__ accum) {
    const int row = blockIdx.x, tid = threadIdx.x;
    __shared__ int nb[ELL_W];
    __shared__ float sred[128];
    const int n = cnt[row];
    if (tid < n) nb[tid] = ell[row * ELL_W + tid];
    __syncthreads();
    float hv = H[(size_t)row * 128 + tid];
    float g = 0.f;
    for (int t = 0; t < n; ++t) g += H[(size_t)nb[t] * 128 + tid];
    float lh = deg[row] * hv - g;
    sred[tid] = hv * lh; __syncthreads();
    for (int s = 64; s; s >>= 1) { if (tid < s) sred[tid] += sred[tid + s]; __syncthreads(); }
    if (tid == 0) atomicAdd(accum + 1, sred[0]);
}

__global__ void finalize_kernel(const float* __restrict__ accum, float* __restrict__ out) {
    out[0] = 100.f * accum[0] + 2.f * accum[1];
}

// ---------------- driver --------------------------------------------------------------------
extern "C" void kernel_launch(void* const* d_in, const int* in_sizes, int n_in,
                              void* d_out, int out_size, void* d_ws, size_t ws_size,
                              hipStream_t stream) {
    const float* X      = (const float*)d_in[0];
    const float* adj    = (const float*)d_in[1];
    const float* W0     = (const float*)d_in[2];
    const float* b0     = (const float*)d_in[3];
    const float* W1     = (const float*)d_in[4];
    const float* b1     = (const float*)d_in[5];
    const float* W2     = (const float*)d_in[6];
    const float* b2     = (const float*)d_in[7];
    const float* attn_W = (const float*)d_in[8];
    const float* a1     = (const float*)d_in[9];
    const float* a2     = (const float*)d_in[10];
    const float* dW0    = (const float*)d_in[11];
    const float* db0    = (const float*)d_in[12];
    const float* dW1    = (const float*)d_in[13];
    const float* db1    = (const float*)d_in[14];
    const float* dW2    = (const float*)d_in[15];
    const float* db2    = (const float*)d_in[16];

    float* out  = (float*)d_out;
    float* Hout = out + 1;
    float* Xr   = out + 1 + (size_t)NN * 128;

    char* w = (char*)d_ws;
    int*   ell   = (int*)w;   w += (size_t)NN * ELL_W * 4;
    int*   cnt   = (int*)w;   w += (size_t)NN * 4;
    float* deg   = (float*)w; w += (size_t)NN * 4;
    float* f1    = (float*)w; w += (size_t)NN * 4;
    float* f2    = (float*)w; w += (size_t)NN * 4;
    float* accum = (float*)w; w += 256;
    float* bufA  = (float*)w; w += (size_t)NN * 512 * 4;      // XW0, later T2
    float* bufB  = (float*)w; w += (size_t)NN * 256 * 4;      // seq_fts
    float* bufC  = (float*)w; w += (size_t)NN * 256 * 4;      // T1
    float* bufH  = (float*)w; w += (size_t)NN * 128 * 4;      // H (aligned)
    unsigned short *XP[3], *W0T[3], *h0P[3], *W1T[3], *h1P[3], *aWR[3], *h2P[3], *W2T[3];
    unsigned short *HP[3], *dW0T[3], *R0P[3], *dW1T[3], *R1P[3], *dW2T[3];
    for (int i = 0; i < 3; ++i) { XP[i]   = (unsigned short*)w; w += (size_t)NN * 1024 * 2; }
    for (int i = 0; i < 3; ++i) { W0T[i]  = (unsigned short*)w; w += (size_t)512 * 1024 * 2; }
    for (int i = 0; i < 3; ++i) { h0P[i]  = (unsigned short*)w; w += (size_t)NN * 512 * 2; }
    for (int i = 0; i < 3; ++i) { W1T[i]  = (unsigned short*)w; w += (size_t)256 * 512 * 2; }
    for (int i = 0; i < 3; ++i) { h1P[i]  = (unsigned short*)w; w += (size_t)NN * 256 * 2; }
    for (int i = 0; i < 3; ++i) { aWR[i]  = (unsigned short*)w; w += (size_t)256 * 256 * 2; }
    for (int i = 0; i < 3; ++i) { h2P[i]  = (unsigned short*)w; w += (size_t)NN * 256 * 2; }
    for (int i = 0; i < 3; ++i) { W2T[i]  = (unsigned short*)w; w += (size_t)128 * 256 * 2; }
    for (int i = 0; i < 3; ++i) { HP[i]   = (unsigned short*)w; w += (size_t)NN * 128 * 2; }
    for (int i = 0; i < 3; ++i) { dW0T[i] = (unsigned short*)w; w += (size_t)256 * 128 * 2; }
    for (int i = 0; i < 3; ++i) { R0P[i]  = (unsigned short*)w; w += (size_t)NN * 256 * 2; }
    for (int i = 0; i < 3; ++i) { dW1T[i] = (unsigned short*)w; w += (size_t)512 * 256 * 2; }
    for (int i = 0; i < 3; ++i) { R1P[i]  = (unsigned short*)w; w += (size_t)NN * 512 * 2; }
    for (int i = 0; i < 3; ++i) { dW2T[i] = (unsigned short*)w; w += (size_t)1024 * 512 * 2; }

    build_ell_kernel<<<dim3(NN / 4), dim3(256), 0, stream>>>(adj, ell, cnt, deg);
    zero_accum_kernel<<<1, 1, 0, stream>>>(accum);

    // weight/input splits (tiled-swizzled planes)
    splitA_kernel<<<4096, 256, 0, stream>>>(X, XP[0], XP[1], XP[2], 1024, NN * 1024 / 8);
    splitBT_kernel<<<256, 256, 0, stream>>>(W0, W0T[0], W0T[1], W0T[2], 1024, 512, 512 * 1024 / 8);
    splitBT_kernel<<<64, 256, 0, stream>>>(W1, W1T[0], W1T[1], W1T[2], 512, 256, 256 * 512 / 8);
    splitBR_kernel<<<32, 256, 0, stream>>>(attn_W, aWR[0], aWR[1], aWR[2], 256, 256 * 256 / 8);
    splitBT_kernel<<<16, 256, 0, stream>>>(W2, W2T[0], W2T[1], W2T[2], 256, 128, 128 * 256 / 8);
    splitBT_kernel<<<16, 256, 0, stream>>>(dW0, dW0T[0], dW0T[1], dW0T[2], 128, 256, 256 * 128 / 8);
    splitBT_kernel<<<64, 256, 0, stream>>>(dW1, dW1T[0], dW1T[1], dW1T[2], 256, 512, 512 * 256 / 8);
    splitBT_kernel<<<256, 256, 0, stream>>>(dW2, dW2T[0], dW2T[1], dW2T[2], 512, 1024, 1024 * 512 / 8);

    // 1. XW0 = X @ W0 (K=1024, N=512)
    mfma_gemm_kernel<0, 0><<<dim3(8, 64), 256, 0, stream>>>(
        XP[0], XP[1], XP[2], W0T[0], W0T[1], W0T[2], nullptr, 1024, 512,
        bufA, nullptr, nullptr, nullptr, nullptr, nullptr);
    // 2. h0 = lrelu(adj@XW0 + b0) -> planes only
    spmm_kernel<512, 0, 1><<<NN / 2, 256, 0, stream>>>(bufA, ell, cnt, b0, nullptr, nullptr, h0P[0], h0P[1], h0P[2]);
    // 3. T1 = h0 @ W1 (K=512, N=256)
    mfma_gemm_kernel<0, 0><<<dim3(4, 64), 256, 0, stream>>>(
        h0P[0], h0P[1], h0P[2], W1T[0], W1T[1], W1T[2], nullptr, 512, 256,
        bufC, nullptr, nullptr, nullptr, nullptr, nullptr);
    // 4. h1 = lrelu(adj@T1 + b1) -> planes only
    spmm_kernel<256, 0, 1><<<NN / 4, 256, 0, stream>>>(bufC, ell, cnt, b1, nullptr, nullptr, h1P[0], h1P[1], h1P[2]);
    // 5. seq_fts = h1 @ attn_W^T (K=256, N=256) -> f32
    mfma_gemm_kernel<0, 0><<<dim3(4, 64), 256, 0, stream>>>(
        h1P[0], h1P[1], h1P[2], aWR[0], aWR[1], aWR[2], nullptr, 256, 256,
        bufB, nullptr, nullptr, nullptr, nullptr, nullptr);
    // 6. f1, f2
    f12_kernel<<<NN / 4, 256, 0, stream>>>(bufB, a1, a2, f1, f2);
    // 7. h2 = attention -> planes only
    attn_kernel<<<NN / 4, 256, 0, stream>>>(bufB, ell, cnt, f1, f2, h2P[0], h2P[1], h2P[2]);
    // 8. T2 = h2 @ W2 (K=256, N=128)
    mfma_gemm_kernel<0, 0><<<dim3(2, 64), 256, 0, stream>>>(
        h2P[0], h2P[1], h2P[2], W2T[0], W2T[1], W2T[2], nullptr, 256, 128,
        bufA, nullptr, nullptr, nullptr, nullptr, nullptr);
    // 9. H = lrelu(adj@T2 + b2) -> f32 (bufH + Hout) + planes
    spmm_kernel<128, 1, 1><<<NN / 8, 256, 0, stream>>>(bufA, ell, cnt, b2, bufH, Hout, HP[0], HP[1], HP[2]);
    // 10. Xr0 = sigmoid(H @ dW0 + db0) (K=128, N=256) -> planes
    mfma_gemm_kernel<1, 1><<<dim3(4, 64), 256, 0, stream>>>(
        HP[0], HP[1], HP[2], dW0T[0], dW0T[1], dW0T[2], db0, 128, 256,
        nullptr, R0P[0], R0P[1], R0P[2], nullptr, nullptr);
    // 11. Xr1 = sigmoid(Xr0 @ dW1 + db1) (K=256, N=512) -> planes
    mfma_gemm_kernel<1, 1><<<dim3(8, 64), 256, 0, stream>>>(
        R0P[0], R0P[1], R0P[2], dW1T[0], dW1T[1], dW1T[2], db1, 256, 512,
        nullptr, R1P[0], R1P[1], R1P[2], nullptr, nullptr);
    // 12. Xr = sigmoid(Xr1 @ dW2 + db2) (K=512, N=1024) -> f32 Xr + fused loss_res
    mfma_gemm_kernel<1, 2><<<dim3(16, 64), 256, 0, stream>>>(
        R1P[0], R1P[1], R1P[2], dW2T[0], dW2T[1], dW2T[2], db2, 512, 1024,
        Xr, nullptr, nullptr, nullptr, X, accum);
    // 13. loss_emb + finalize
    loss_emb_kernel<<<NN, 128, 0, stream>>>(bufH, ell, cnt, deg, accum);
    finalize_kernel<<<1, 1, 0, stream>>>(accum, out);
}

// Round 9
// 828.729 us; speedup vs baseline: 1.3546x; 1.1215x over previous
//
#include <hip/hip_runtime.h>
#include <math.h>

#define NN 8192
#define ELL_W 128
#define ASCL 0.015625f   // 2^-6: activation-split scale (fp16 headroom 65504*64 ~ 4.2e6)

typedef _Float16 f16x8 __attribute__((ext_vector_type(8)));
typedef __attribute__((ext_vector_type(4))) float f32x4;

__device__ __forceinline__ float lrelu(float x) { return x > 0.f ? x : 0.01f * x; }

// fp16x2 split: v = h0 + h1 + O(2^-22 |v|). Clamp guards the Inf->NaN path (|v|>65504
// would give +Inf/-Inf planes whose MFMA products produce NaN — R7's failure mode).
__device__ __forceinline__ void split2(float v, unsigned short& u0, unsigned short& u1) {
    v = fminf(fmaxf(v, -60000.f), 60000.f);
    _Float16 a = (_Float16)v;
    float r = v - (float)a;
    _Float16 b = (_Float16)r;
    u0 = *(unsigned short*)&a;
    u1 = *(unsigned short*)&b;
}

// async global->LDS, 16B per lane; LDS dest = wave-uniform base + lane*16
__device__ __forceinline__ void gload_lds16(const unsigned short* g, unsigned short* l) {
    __builtin_amdgcn_global_load_lds((const __attribute__((address_space(1))) unsigned int*)g,
                                     (__attribute__((address_space(3))) unsigned int*)l, 16, 0, 0);
}

// ---- plane layout: A (MxK): [M/128][K/32] tiles of [r:128][pc:4][e:8], pc=(c+(r>>1))&3.
//      B (NxK): [N/64][K/32] tiles of [r:64][pc:4][e:8], same swizzle.
__device__ __forceinline__ size_t a_plane_off(int rowg, int kg, int K) {
    int rr = rowg & 127, kk = kg & 31;
    int pc = (((kk >> 3) + (rr >> 1)) & 3);
    return ((size_t)(rowg >> 7) * (K >> 5) + (kg >> 5)) * 4096 + rr * 32 + pc * 8 + (kk & 7);
}

// ---------------- ELL build ----------------------------------------------------------------
__global__ void build_ell_kernel(const float* __restrict__ adj, int* __restrict__ ell,
                                 int* __restrict__ cnt, float* __restrict__ deg) {
    const int row  = blockIdx.x * 4 + (threadIdx.x >> 6);
    const int lane = threadIdx.x & 63;
    const float4* arow = (const float4*)(adj + (size_t)row * NN);
    const unsigned long long lmask = (1ull << lane) - 1ull;
    int count = 0;
    for (int c0 = 0; c0 < NN; c0 += 256) {
        const float4 v = arow[(c0 >> 2) + lane];
        const int col = c0 + lane * 4;
        float f[4] = {v.x, v.y, v.z, v.w};
        #pragma unroll
        for (int q = 0; q < 4; ++q) {
            unsigned long long m = __ballot(f[q] > 0.f);
            if (f[q] > 0.f) {
                int pos = count + __popcll(m & lmask);
                if (pos < ELL_W) ell[row * ELL_W + pos] = col + q;
            }
            count += __popcll(m);
        }
    }
    if (lane == 0) {
        cnt[row] = count < ELL_W ? count : ELL_W;
        deg[row] = (float)count;
    }
}

__global__ void zero_accum_kernel(float* accum) { accum[0] = 0.f; accum[1] = 0.f; }

// ---------------- split kernels (emit tiled-swizzled fp16 planes) ---------------------------
__global__ void splitA_kernel(const float* __restrict__ src, unsigned short* __restrict__ P0,
                              unsigned short* __restrict__ P1, int K, int nchunks) {
    int g = blockIdx.x * 256 + threadIdx.x;
    if (g >= nchunks) return;
    const int KT = K >> 5;
    int t = g >> 9, w = g & 511;                 // 512 chunks per 128x32 tile
    int r = w >> 2, pc = w & 3;
    int c = (pc - (r >> 1)) & 3;
    int tm = t / KT, tk = t % KT;
    const float* s = src + (size_t)(tm * 128 + r) * K + tk * 32 + c * 8;
    const float4 v0 = *(const float4*)s, v1 = *(const float4*)(s + 4);
    float f[8] = {v0.x, v0.y, v0.z, v0.w, v1.x, v1.y, v1.z, v1.w};
    unsigned short a0[8], a1[8];
    #pragma unroll
    for (int j = 0; j < 8; ++j) split2(f[j], a0[j], a1[j]);
    *(uint4*)(P0 + (size_t)g * 8) = *(uint4*)a0;
    *(uint4*)(P1 + (size_t)g * 8) = *(uint4*)a1;
}

// W [K][N] row-major (transpose) -> B-planes [N/64][K/32]
__global__ void splitBT_kernel(const float* __restrict__ W, unsigned short* __restrict__ P0,
                               unsigned short* __restrict__ P1, int K, int N, int nchunks) {
    int g = blockIdx.x * 256 + threadIdx.x;
    if (g >= nchunks) return;
    const int KT = K >> 5;
    int t = g >> 8, w = g & 255;                 // 256 chunks per 64x32 tile
    int r = w >> 2, pc = w & 3;
    int c = (pc - (r >> 1)) & 3;
    int tn = t / KT, tk = t % KT;
    const float* s = W + (size_t)(tk * 32 + c * 8) * N + tn * 64 + r;
    unsigned short a0[8], a1[8];
    #pragma unroll
    for (int j = 0; j < 8; ++j) split2(s[(size_t)j * N], a0[j], a1[j]);
    *(uint4*)(P0 + (size_t)g * 8) = *(uint4*)a0;
    *(uint4*)(P1 + (size_t)g * 8) = *(uint4*)a1;
}

// Wrow [N][K] row-major -> B-planes
__global__ void splitBR_kernel(const float* __restrict__ W, unsigned short* __restrict__ P0,
                               unsigned short* __restrict__ P1, int K, int nchunks) {
    int g = blockIdx.x * 256 + threadIdx.x;
    if (g >= nchunks) return;
    const int KT = K >> 5;
    int t = g >> 8, w = g & 255;
    int r = w >> 2, pc = w & 3;
    int c = (pc - (r >> 1)) & 3;
    int tn = t / KT, tk = t % KT;
    const float* s = W + (size_t)(tn * 64 + r) * K + tk * 32 + c * 8;
    const float4 v0 = *(const float4*)s, v1 = *(const float4*)(s + 4);
    float f[8] = {v0.x, v0.y, v0.z, v0.w, v1.x, v1.y, v1.z, v1.w};
    unsigned short a0[8], a1[8];
    #pragma unroll
    for (int j = 0; j < 8; ++j) split2(f[j], a0[j], a1[j]);
    *(uint4*)(P0 + (size_t)g * 8) = *(uint4*)a0;
    *(uint4*)(P1 + (size_t)g * 8) = *(uint4*)a1;
}

// ---------------- fp16x2 MFMA GEMM (3 products, global_load_lds, XCD swizzle) ---------------
// C = act(ascale*(A@B^T)(+bias)). ascale=64 undoes the 2^-6 activation-split scale.
// TM=128: wave 64x32 (MI=4); TM=64: wave 32x32 (MI=2). BN=64, BK=32.
// ACT: 1 = sigmoid(x+bias). OUT: 0 = f32 C; 1 = A-planes of C (K2=N); 2 = f32 C + loss_res.
template <int TM, int ACT, int OUT>
__launch_bounds__(256)
__global__ void mfma_gemm_kernel(const unsigned short* __restrict__ A0, const unsigned short* __restrict__ A1,
                                 const unsigned short* __restrict__ B0, const unsigned short* __restrict__ B1,
                                 const float* __restrict__ bias, int K, int N, float ascale,
                                 float* __restrict__ Cf,
                                 unsigned short* __restrict__ C0, unsigned short* __restrict__ C1,
                                 const float* __restrict__ Xref, float* __restrict__ accum) {
    constexpr int MI  = TM / 32;                  // MFMA row-fragments per wave
    constexpr int APL = TM * 32;                  // ushorts per A-plane K-tile in LDS
    constexpr int ASEG = TM / 16;                 // 1KB segments per A plane
    __shared__ __align__(16) unsigned short lds[2 * APL + 4096];
    const int tid = threadIdx.x, lane = tid & 63, wv = tid >> 6;
    const int KT = K >> 5;
    // XCD-chunked swizzle: 8 consecutive-id blocks share one XCD -> A-panel L2-resident.
    const int nx = gridDim.x;
    const int id = blockIdx.y * nx + blockIdx.x;
    const int cpx = (nx * gridDim.y) >> 3;        // all grids have nwg % 8 == 0
    const int lid = (id & 7) * cpx + (id >> 3);
    const int bxx = lid % nx, byy = lid / nx;
    const int bm = byy * TM, bn = bxx * 64;
    const int wr = (wv >> 1) * (TM / 2), wc = (wv & 1) * 32;
    const int lr = lane & 15, cch = lane >> 4;

    const size_t abase = (size_t)(bm >> 7) * KT * 4096 + (bm & 127) * 32;
    const unsigned short* Ap[2] = {A0 + abase, A1 + abase};
    const unsigned short* Bp[2] = {B0 + (size_t)bxx * KT * 2048, B1 + (size_t)bxx * KT * 2048};
    int offA[MI], offB[2];
    #pragma unroll
    for (int mi = 0; mi < MI; ++mi) { int r = wr + mi * 16 + lr; offA[mi] = r * 32 + (((cch + (r >> 1)) & 3) << 3); }
    #pragma unroll
    for (int ni = 0; ni < 2; ++ni) { int r = wc + ni * 16 + lr; offB[ni] = r * 32 + (((cch + (r >> 1)) & 3) << 3); }

    f32x4 acc[MI][2];
    #pragma unroll
    for (int i = 0; i < MI; ++i)
        #pragma unroll
        for (int j = 0; j < 2; ++j) acc[i][j] = (f32x4){0.f, 0.f, 0.f, 0.f};

    for (int tk = 0; tk < KT; ++tk) {
        #pragma unroll
        for (int i = 0; i < 2 * ASEG / 4; ++i) {  // A: 2 planes x ASEG 1KB segments
            int s = i * 4 + wv, p = s / ASEG, q = s % ASEG;
            gload_lds16(Ap[p] + (size_t)tk * 4096 + q * 512 + lane * 8, &lds[p * APL + q * 512]);
        }
        #pragma unroll
        for (int i = 0; i < 2; ++i) {             // B: 2 planes x 4 segments
            int s = i * 4 + wv, p = s >> 2, q = s & 3;
            gload_lds16(Bp[p] + (size_t)tk * 2048 + q * 512 + lane * 8, &lds[2 * APL + p * 2048 + q * 512]);
        }
        __syncthreads();                          // drains vmcnt -> tile ready
        f16x8 af[2][MI], bfr[2][2];
        #pragma unroll
        for (int p = 0; p < 2; ++p) {
            #pragma unroll
            for (int mi = 0; mi < MI; ++mi) af[p][mi] = *(const f16x8*)&lds[p * APL + offA[mi]];
            #pragma unroll
            for (int ni = 0; ni < 2; ++ni) bfr[p][ni] = *(const f16x8*)&lds[2 * APL + p * 2048 + offB[ni]];
        }
        #pragma unroll
        for (int mi = 0; mi < MI; ++mi)
            #pragma unroll
            for (int ni = 0; ni < 2; ++ni) {
                f32x4 c = acc[mi][ni];
                c = __builtin_amdgcn_mfma_f32_16x16x32_f16(af[0][mi], bfr[0][ni], c, 0, 0, 0);
                c = __builtin_amdgcn_mfma_f32_16x16x32_f16(af[0][mi], bfr[1][ni], c, 0, 0, 0);
                c = __builtin_amdgcn_mfma_f32_16x16x32_f16(af[1][mi], bfr[0][ni], c, 0, 0, 0);
                acc[mi][ni] = c;
            }
        __syncthreads();                          // reads done before next overwrite
    }
    float local = 0.f;
    #pragma unroll
    for (int mi = 0; mi < MI; ++mi)
        #pragma unroll
        for (int ni = 0; ni < 2; ++ni) {
            const int colg = bn + wc + ni * 16 + lr;
            #pragma unroll
            for (int r = 0; r < 4; ++r) {
                const int rowg = bm + wr + mi * 16 + cch * 4 + r;
                float v = acc[mi][ni][r] * ascale;
                if (ACT) { v += bias[colg]; v = 1.f / (1.f + __expf(-v)); }
                if (OUT == 0) {
                    Cf[(size_t)rowg * N + colg] = v;
                } else if (OUT == 1) {            // emit A-planes for next GEMM (K2 = N)
                    size_t po = a_plane_off(rowg, colg, N);
                    unsigned short h0, h1; split2(v, h0, h1);
                    C0[po] = h0; C1[po] = h1;
                } else {
                    const size_t o = (size_t)rowg * N + colg;
                    Cf[o] = v;
                    float x = Xref[o];
                    float d = (v - x) * fmaf(x, 24.f, 1.f);
                    local = fmaf(d, d, local);
                }
            }
        }
    if (OUT == 2) {
        float* sred = (float*)lds;                // LDS free after last K-step barrier
        sred[tid] = local; __syncthreads();
        for (int s = 128; s; s >>= 1) { if (tid < s) sred[tid] += sred[tid + s]; __syncthreads(); }
        if (tid == 0) atomicAdd(accum, sred[0]);
    }
}

// ---------------- adj @ M gather-sum + bias + lrelu -----------------------------------------
// OUTF: f32 out (+ optional scalar out2). OUTP: emit fp16x2 A-planes of v*2^-6 (K=C).
template <int C, int OUTF, int OUTP>
__global__ void spmm_kernel(const float* __restrict__ M_, const int* __restrict__ ell,
                            const int* __restrict__ cnt, const float* __restrict__ bias,
                            float* __restrict__ out, float* __restrict__ out2,
                            unsigned short* __restrict__ P0, unsigned short* __restrict__ P1) {
    constexpr int TPR = C / 4;
    constexpr int RPB = 256 / TPR;
    const int rid = threadIdx.x / TPR;
    const int c4  = threadIdx.x % TPR;
    const int row = blockIdx.x * RPB + rid;
    __shared__ int nb_s[RPB][ELL_W];
    const int n = cnt[row];
    for (int t = c4; t < n; t += TPR) nb_s[rid][t] = ell[row * ELL_W + t];
    __syncthreads();
    float4 acc = {0.f, 0.f, 0.f, 0.f};
    for (int t = 0; t < n; ++t) {
        const float4 v = *(const float4*)(M_ + (size_t)nb_s[rid][t] * C + c4 * 4);
        acc.x += v.x; acc.y += v.y; acc.z += v.z; acc.w += v.w;
    }
    const float4 bv = *(const float4*)(bias + c4 * 4);
    float4 r;
    r.x = lrelu(acc.x + bv.x); r.y = lrelu(acc.y + bv.y);
    r.z = lrelu(acc.z + bv.z); r.w = lrelu(acc.w + bv.w);
    if (OUTF) {
        *(float4*)(out + (size_t)row * C + c4 * 4) = r;
        if (out2) {                               // +4B-misaligned d_out region: scalar
            size_t o = (size_t)row * C + c4 * 4;
            out2[o] = r.x; out2[o + 1] = r.y; out2[o + 2] = r.z; out2[o + 3] = r.w;
        }
    }
    if (OUTP) {
        constexpr int KT = C >> 5;
        int tm = row >> 7, rr = row & 127;
        int tk = c4 >> 3, cc = (c4 >> 1) & 3, h = c4 & 1;
        int pc = (cc + (rr >> 1)) & 3;
        size_t off = ((size_t)tm * KT + tk) * 4096 + rr * 32 + pc * 8 + h * 4;
        ushort4 q0, q1;
        split2(r.x * ASCL, q0.x, q1.x); split2(r.y * ASCL, q0.y, q1.y);
        split2(r.z * ASCL, q0.z, q1.z); split2(r.w * ASCL, q0.w, q1.w);
        *(ushort4*)(P0 + off) = q0; *(ushort4*)(P1 + off) = q1;
    }
}

// ---------------- f1 = seq@a1, f2 = seq@a2 --------------------------------------------------
__global__ void f12_kernel(const float* __restrict__ seq, const float* __restrict__ a1,
                           const float* __restrict__ a2, float* __restrict__ f1,
                           float* __restrict__ f2) {
    const int row = blockIdx.x * 4 + (threadIdx.x >> 6);
    const int lane = threadIdx.x & 63;
    const float4 v  = *(const float4*)(seq + (size_t)row * 256 + lane * 4);
    const float4 w1 = *(const float4*)(a1 + lane * 4);
    const float4 w2 = *(const float4*)(a2 + lane * 4);
    float s1 = v.x * w1.x + v.y * w1.y + v.z * w1.z + v.w * w1.w;
    float s2 = v.x * w2.x + v.y * w2.y + v.z * w2.z + v.w * w2.w;
    #pragma unroll
    for (int o = 32; o; o >>= 1) { s1 += __shfl_xor(s1, o); s2 += __shfl_xor(s2, o); }
    if (lane == 0) { f1[row] = s1; f2[row] = s2; }
}

// ---------------- sparse GAT -> fp16x2 A-planes of h2*2^-6 (K=256) --------------------------
__global__ void attn_kernel(const float* __restrict__ seq, const int* __restrict__ ell,
                            const int* __restrict__ cnt, const float* __restrict__ f1,
                            const float* __restrict__ f2,
                            unsigned short* __restrict__ P0, unsigned short* __restrict__ P1) {
    const int wid = threadIdx.x >> 6, lane = threadIdx.x & 63;
    const int row = blockIdx.x * 4 + wid;
    __shared__ int   nb_s[4][ELL_W];
    __shared__ float cf_s[4][ELL_W];
    const int n = cnt[row];
    const float f1r = f1[row];
    float m = -3.0e38f;
    for (int t = lane; t < n; t += 64) {
        int j = ell[row * ELL_W + t];
        nb_s[wid][t] = j;
        float v = lrelu(f1r + f2[j]);
        cf_s[wid][t] = v;
        m = fmaxf(m, v);
    }
    #pragma unroll
    for (int o = 32; o; o >>= 1) m = fmaxf(m, __shfl_xor(m, o));
    __syncthreads();
    float s = 0.f;
    for (int t = lane; t < n; t += 64) {
        float e = __expf(cf_s[wid][t] - m);
        cf_s[wid][t] = e;
        s += e;
    }
    #pragma unroll
    for (int o = 32; o; o >>= 1) s += __shfl_xor(s, o);
    const float inv = 1.f / s;
    __syncthreads();
    float4 acc = {0.f, 0.f, 0.f, 0.f};
    for (int t = 0; t < n; ++t) {
        const float c = cf_s[wid][t];
        const float4 v = *(const float4*)(seq + (size_t)nb_s[wid][t] * 256 + lane * 4);
        acc.x = fmaf(c, v.x, acc.x); acc.y = fmaf(c, v.y, acc.y);
        acc.z = fmaf(c, v.z, acc.z); acc.w = fmaf(c, v.w, acc.w);
    }
    float4 r;
    r.x = lrelu(acc.x * inv); r.y = lrelu(acc.y * inv);
    r.z = lrelu(acc.z * inv); r.w = lrelu(acc.w * inv);
    int tm = row >> 7, rr = row & 127;
    int tk = lane >> 3, cc = (lane >> 1) & 3, h = lane & 1;
    int pc = (cc + (rr >> 1)) & 3;
    size_t off = ((size_t)tm * 8 + tk) * 4096 + rr * 32 + pc * 8 + h * 4;
    ushort4 q0, q1;
    split2(r.x * ASCL, q0.x, q1.x); split2(r.y * ASCL, q0.y, q1.y);
    split2(r.z * ASCL, q0.z, q1.z); split2(r.w * ASCL, q0.w, q1.w);
    *(ushort4*)(P0 + off) = q0; *(ushort4*)(P1 + off) = q1;
}

// ---------------- loss_emb ------------------------------------------------------------------
__global__ void loss_emb_kernel(const float* __restrict__ H, const int* __restrict__ ell,
                                const int* __restrict__ cnt, const float* __restrict__ deg,
                                float* __restrict__ accum) {
    const int row = blockIdx.x, tid = threadIdx.x;
    __shared__ int nb[ELL_W];
    __shared__ float sred[128];
    const int n = cnt[row];
    if (tid < n) nb[tid] = ell[row * ELL_W + tid];
    __syncthreads();
    float hv = H[(size_t)row * 128 + tid];
    float g = 0.f;
    for (int t = 0; t < n; ++t) g += H[(size_t)nb[t] * 128 + tid];
    float lh = deg[row] * hv - g;
    sred[tid] = hv * lh; __syncthreads();
    for (int s = 64; s; s >>= 1) { if (tid < s) sred[tid] += sred[tid + s]; __syncthreads(); }
    if (tid == 0) atomicAdd(accum + 1, sred[0]);
}

__global__ void finalize_kernel(const float* __restrict__ accum, float* __restrict__ out) {
    out[0] = 100.f * accum[0] + 2.f * accum[1];
}

// ---------------- driver --------------------------------------------------------------------
extern "C" void kernel_launch(void* const* d_in, const int* in_sizes, int n_in,
                              void* d_out, int out_size, void* d_ws, size_t ws_size,
                              hipStream_t stream) {
    const float* X      = (const float*)d_in[0];
    const float* adj    = (const float*)d_in[1];
    const float* W0     = (const float*)d_in[2];
    const float* b0     = (const float*)d_in[3];
    const float* W1     = (const float*)d_in[4];
    const float* b1     = (const float*)d_in[5];
    const float* W2     = (const float*)d_in[6];
    const float* b2     = (const float*)d_in[7];
    const float* attn_W = (const float*)d_in[8];
    const float* a1     = (const float*)d_in[9];
    const float* a2     = (const float*)d_in[10];
    const float* dW0    = (const float*)d_in[11];
    const float* db0    = (const float*)d_in[12];
    const float* dW1    = (const float*)d_in[13];
    const float* db1    = (const float*)d_in[14];
    const float* dW2    = (const float*)d_in[15];
    const float* db2    = (const float*)d_in[16];

    float* out  = (float*)d_out;
    float* Hout = out + 1;
    float* Xr   = out + 1 + (size_t)NN * 128;

    char* w = (char*)d_ws;
    int*   ell   = (int*)w;   w += (size_t)NN * ELL_W * 4;
    int*   cnt   = (int*)w;   w += (size_t)NN * 4;
    float* deg   = (float*)w; w += (size_t)NN * 4;
    float* f1    = (float*)w; w += (size_t)NN * 4;
    float* f2    = (float*)w; w += (size_t)NN * 4;
    float* accum = (float*)w; w += 256;
    float* bufA  = (float*)w; w += (size_t)NN * 512 * 4;      // XW0, later T2
    float* bufB  = (float*)w; w += (size_t)NN * 256 * 4;      // seq_fts
    float* bufC  = (float*)w; w += (size_t)NN * 256 * 4;      // T1
    float* bufH  = (float*)w; w += (size_t)NN * 128 * 4;      // H (aligned)
    unsigned short *XP[2], *W0T[2], *h0P[2], *W1T[2], *h1P[2], *aWR[2], *h2P[2], *W2T[2];
    unsigned short *HP[2], *dW0T[2], *R0P[2], *dW1T[2], *R1P[2], *dW2T[2];
    for (int i = 0; i < 2; ++i) { XP[i]   = (unsigned short*)w; w += (size_t)NN * 1024 * 2; }
    for (int i = 0; i < 2; ++i) { W0T[i]  = (unsigned short*)w; w += (size_t)512 * 1024 * 2; }
    for (int i = 0; i < 2; ++i) { h0P[i]  = (unsigned short*)w; w += (size_t)NN * 512 * 2; }
    for (int i = 0; i < 2; ++i) { W1T[i]  = (unsigned short*)w; w += (size_t)256 * 512 * 2; }
    for (int i = 0; i < 2; ++i) { h1P[i]  = (unsigned short*)w; w += (size_t)NN * 256 * 2; }
    for (int i = 0; i < 2; ++i) { aWR[i]  = (unsigned short*)w; w += (size_t)256 * 256 * 2; }
    for (int i = 0; i < 2; ++i) { h2P[i]  = (unsigned short*)w; w += (size_t)NN * 256 * 2; }
    for (int i = 0; i < 2; ++i) { W2T[i]  = (unsigned short*)w; w += (size_t)128 * 256 * 2; }
    for (int i = 0; i < 2; ++i) { HP[i]   = (unsigned short*)w; w += (size_t)NN * 128 * 2; }
    for (int i = 0; i < 2; ++i) { dW0T[i] = (unsigned short*)w; w += (size_t)256 * 128 * 2; }
    for (int i = 0; i < 2; ++i) { R0P[i]  = (unsigned short*)w; w += (size_t)NN * 256 * 2; }
    for (int i = 0; i < 2; ++i) { dW1T[i] = (unsigned short*)w; w += (size_t)512 * 256 * 2; }
    for (int i = 0; i < 2; ++i) { R1P[i]  = (unsigned short*)w; w += (size_t)NN * 512 * 2; }
    for (int i = 0; i < 2; ++i) { dW2T[i] = (unsigned short*)w; w += (size_t)1024 * 512 * 2; }

    build_ell_kernel<<<dim3(NN / 4), dim3(256), 0, stream>>>(adj, ell, cnt, deg);
    zero_accum_kernel<<<1, 1, 0, stream>>>(accum);

    // splits (fp16x2, tiled-swizzled planes; X/weights unscaled — all bounded ~6)
    splitA_kernel<<<4096, 256, 0, stream>>>(X, XP[0], XP[1], 1024, NN * 1024 / 8);
    splitBT_kernel<<<256, 256, 0, stream>>>(W0, W0T[0], W0T[1], 1024, 512, 512 * 1024 / 8);
    splitBT_kernel<<<64, 256, 0, stream>>>(W1, W1T[0], W1T[1], 512, 256, 256 * 512 / 8);
    splitBR_kernel<<<32, 256, 0, stream>>>(attn_W, aWR[0], aWR[1], 256, 256 * 256 / 8);
    splitBT_kernel<<<16, 256, 0, stream>>>(W2, W2T[0], W2T[1], 256, 128, 128 * 256 / 8);
    splitBT_kernel<<<16, 256, 0, stream>>>(dW0, dW0T[0], dW0T[1], 128, 256, 256 * 128 / 8);
    splitBT_kernel<<<64, 256, 0, stream>>>(dW1, dW1T[0], dW1T[1], 256, 512, 512 * 256 / 8);
    splitBT_kernel<<<256, 256, 0, stream>>>(dW2, dW2T[0], dW2T[1], 512, 1024, 1024 * 512 / 8);

    // 1. XW0 = X @ W0 (K=1024, N=512), TM=128, ascale=1
    mfma_gemm_kernel<128, 0, 0><<<dim3(8, 64), 256, 0, stream>>>(
        XP[0], XP[1], W0T[0], W0T[1], nullptr, 1024, 512, 1.f, bufA, nullptr, nullptr, nullptr, nullptr);
    // 2. h0 = lrelu(adj@XW0 + b0) -> planes (x2^-6)
    spmm_kernel<512, 0, 1><<<NN / 2, 256, 0, stream>>>(bufA, ell, cnt, b0, nullptr, nullptr, h0P[0], h0P[1]);
    // 3. T1 = h0 @ W1 (K=512, N=256), TM=64, ascale=64
    mfma_gemm_kernel<64, 0, 0><<<dim3(4, 128), 256, 0, stream>>>(
        h0P[0], h0P[1], W1T[0], W1T[1], nullptr, 512, 256, 64.f, bufC, nullptr, nullptr, nullptr, nullptr);
    // 4. h1 = lrelu(adj@T1 + b1) -> planes (x2^-6)
    spmm_kernel<256, 0, 1><<<NN / 4, 256, 0, stream>>>(bufC, ell, cnt, b1, nullptr, nullptr, h1P[0], h1P[1]);
    // 5. seq_fts = h1 @ attn_W^T (K=256, N=256), TM=64, ascale=64 -> f32
    mfma_gemm_kernel<64, 0, 0><<<dim3(4, 128), 256, 0, stream>>>(
        h1P[0], h1P[1], aWR[0], aWR[1], nullptr, 256, 256, 64.f, bufB, nullptr, nullptr, nullptr, nullptr);
    // 6. f1, f2
    f12_kernel<<<NN / 4, 256, 0, stream>>>(bufB, a1, a2, f1, f2);
    // 7. h2 = attention -> planes (x2^-6)
    attn_kernel<<<NN / 4, 256, 0, stream>>>(bufB, ell, cnt, f1, f2, h2P[0], h2P[1]);
    // 8. T2 = h2 @ W2 (K=256, N=128), TM=64, ascale=64
    mfma_gemm_kernel<64, 0, 0><<<dim3(2, 128), 256, 0, stream>>>(
        h2P[0], h2P[1], W2T[0], W2T[1], nullptr, 256, 128, 64.f, bufA, nullptr, nullptr, nullptr, nullptr);
    // 9. H = lrelu(adj@T2 + b2) -> f32 (bufH + Hout) + planes (x2^-6)
    spmm_kernel<128, 1, 1><<<NN / 8, 256, 0, stream>>>(bufA, ell, cnt, b2, bufH, Hout, HP[0], HP[1]);
    // 10. Xr0 = sigmoid(64*(H/64 @ dW0) + db0) (K=128, N=256), TM=64 -> planes (unscaled: sigmoid<=1)
    mfma_gemm_kernel<64, 1, 1><<<dim3(4, 128), 256, 0, stream>>>(
        HP[0], HP[1], dW0T[0], dW0T[1], db0, 128, 256, 64.f, nullptr, R0P[0], R0P[1], nullptr, nullptr);
    // 11. Xr1 = sigmoid(Xr0 @ dW1 + db1) (K=256, N=512), TM=128, ascale=1 -> planes
    mfma_gemm_kernel<128, 1, 1><<<dim3(8, 64), 256, 0, stream>>>(
        R0P[0], R0P[1], dW1T[0], dW1T[1], db1, 256, 512, 1.f, nullptr, R1P[0], R1P[1], nullptr, nullptr);
    // 12. Xr = sigmoid(Xr1 @ dW2 + db2) (K=512, N=1024), TM=128, ascale=1 -> f32 Xr + loss_res
    mfma_gemm_kernel<128, 1, 2><<<dim3(16, 64), 256, 0, stream>>>(
        R1P[0], R1P[1], dW2T[0], dW2T[1], db2, 512, 1024, 1.f, Xr, nullptr, nullptr, X, accum);
    // 13. loss_emb + finalize
    loss_emb_kernel<<<NN, 128, 0, stream>>>(bufH, ell, cnt, deg, accum);
    finalize_kernel<<<1, 1, 0, stream>>>(accum, out);
}

// Round 10
// 750.476 us; speedup vs baseline: 1.4958x; 1.1043x over previous
//
#include <hip/hip_runtime.h>
#include <math.h>

#define NN 8192
#define ELL_W 128
#define ASCL 0.015625f   // 2^-6: activation-split scale (fp16 headroom 65504*64 ~ 4.2e6)

typedef _Float16 f16x8 __attribute__((ext_vector_type(8)));
typedef _Float16 f16x4 __attribute__((ext_vector_type(4)));
typedef __attribute__((ext_vector_type(4))) float f32x4;

__device__ __forceinline__ float lrelu(float x) { return x > 0.f ? x : 0.01f * x; }

// fp16x2 split: v = h0 + h1 + O(2^-22 |v|). Clamp guards the Inf->NaN path (R7 failure).
__device__ __forceinline__ void split2(float v, unsigned short& u0, unsigned short& u1) {
    v = fminf(fmaxf(v, -60000.f), 60000.f);
    _Float16 a = (_Float16)v;
    float r = v - (float)a;
    _Float16 b = (_Float16)r;
    u0 = *(unsigned short*)&a;
    u1 = *(unsigned short*)&b;
}
__device__ __forceinline__ unsigned short f2h(float v) {
    v = fminf(fmaxf(v, -60000.f), 60000.f);
    _Float16 a = (_Float16)v;
    return *(unsigned short*)&a;
}

// async global->LDS, 16B per lane; LDS dest = wave-uniform base + lane*16
__device__ __forceinline__ void gload_lds16(const unsigned short* g, unsigned short* l) {
    __builtin_amdgcn_global_load_lds((const __attribute__((address_space(1))) unsigned int*)g,
                                     (__attribute__((address_space(3))) unsigned int*)l, 16, 0, 0);
}

// ---- plane layout: A (MxK): [M/128][K/32] tiles of [r:128][pc:4][e:8], pc=(c+(r>>1))&3.
//      B (NxK): [N/64][K/32] tiles of [r:64][pc:4][e:8], same swizzle.
__device__ __forceinline__ size_t a_plane_off(int rowg, int kg, int K) {
    int rr = rowg & 127, kk = kg & 31;
    int pc = (((kk >> 3) + (rr >> 1)) & 3);
    return ((size_t)(rowg >> 7) * (K >> 5) + (kg >> 5)) * 4096 + rr * 32 + pc * 8 + (kk & 7);
}

// ---------------- ELL build ----------------------------------------------------------------
__global__ void build_ell_kernel(const float* __restrict__ adj, int* __restrict__ ell,
                                 int* __restrict__ cnt, float* __restrict__ deg) {
    const int row  = blockIdx.x * 4 + (threadIdx.x >> 6);
    const int lane = threadIdx.x & 63;
    const float4* arow = (const float4*)(adj + (size_t)row * NN);
    const unsigned long long lmask = (1ull << lane) - 1ull;
    int count = 0;
    for (int c0 = 0; c0 < NN; c0 += 256) {
        const float4 v = arow[(c0 >> 2) + lane];
        const int col = c0 + lane * 4;
        float f[4] = {v.x, v.y, v.z, v.w};
        #pragma unroll
        for (int q = 0; q < 4; ++q) {
            unsigned long long m = __ballot(f[q] > 0.f);
            if (f[q] > 0.f) {
                int pos = count + __popcll(m & lmask);
                if (pos < ELL_W) ell[row * ELL_W + pos] = col + q;
            }
            count += __popcll(m);
        }
    }
    if (lane == 0) {
        cnt[row] = count < ELL_W ? count : ELL_W;
        deg[row] = (float)count;
    }
}

__global__ void zero_accum_kernel(float* accum) { accum[0] = 0.f; accum[1] = 0.f; }

// ---------------- split kernels (emit tiled-swizzled fp16 planes) ---------------------------
__global__ void splitA_kernel(const float* __restrict__ src, unsigned short* __restrict__ P0,
                              unsigned short* __restrict__ P1, int K, int nchunks) {
    int g = blockIdx.x * 256 + threadIdx.x;
    if (g >= nchunks) return;
    const int KT = K >> 5;
    int t = g >> 9, w = g & 511;                 // 512 chunks per 128x32 tile
    int r = w >> 2, pc = w & 3;
    int c = (pc - (r >> 1)) & 3;
    int tm = t / KT, tk = t % KT;
    const float* s = src + (size_t)(tm * 128 + r) * K + tk * 32 + c * 8;
    const float4 v0 = *(const float4*)s, v1 = *(const float4*)(s + 4);
    float f[8] = {v0.x, v0.y, v0.z, v0.w, v1.x, v1.y, v1.z, v1.w};
    unsigned short a0[8], a1[8];
    #pragma unroll
    for (int j = 0; j < 8; ++j) split2(f[j], a0[j], a1[j]);
    *(uint4*)(P0 + (size_t)g * 8) = *(uint4*)a0;
    *(uint4*)(P1 + (size_t)g * 8) = *(uint4*)a1;
}

// W [K][N] row-major (transpose) -> B-planes [N/64][K/32]
__global__ void splitBT_kernel(const float* __restrict__ W, unsigned short* __restrict__ P0,
                               unsigned short* __restrict__ P1, int K, int N, int nchunks) {
    int g = blockIdx.x * 256 + threadIdx.x;
    if (g >= nchunks) return;
    const int KT = K >> 5;
    int t = g >> 8, w = g & 255;                 // 256 chunks per 64x32 tile
    int r = w >> 2, pc = w & 3;
    int c = (pc - (r >> 1)) & 3;
    int tn = t / KT, tk = t % KT;
    const float* s = W + (size_t)(tk * 32 + c * 8) * N + tn * 64 + r;
    unsigned short a0[8], a1[8];
    #pragma unroll
    for (int j = 0; j < 8; ++j) split2(s[(size_t)j * N], a0[j], a1[j]);
    *(uint4*)(P0 + (size_t)g * 8) = *(uint4*)a0;
    *(uint4*)(P1 + (size_t)g * 8) = *(uint4*)a1;
}

// Wrow [N][K] row-major -> B-planes
__global__ void splitBR_kernel(const float* __restrict__ W, unsigned short* __restrict__ P0,
                               unsigned short* __restrict__ P1, int K, int nchunks) {
    int g = blockIdx.x * 256 + threadIdx.x;
    if (g >= nchunks) return;
    const int KT = K >> 5;
    int t = g >> 8, w = g & 255;
    int r = w >> 2, pc = w & 3;
    int c = (pc - (r >> 1)) & 3;
    int tn = t / KT, tk = t % KT;
    const float* s = W + (size_t)(tn * 64 + r) * K + tk * 32 + c * 8;
    const float4 v0 = *(const float4*)s, v1 = *(const float4*)(s + 4);
    float f[8] = {v0.x, v0.y, v0.z, v0.w, v1.x, v1.y, v1.z, v1.w};
    unsigned short a0[8], a1[8];
    #pragma unroll
    for (int j = 0; j < 8; ++j) split2(f[j], a0[j], a1[j]);
    *(uint4*)(P0 + (size_t)g * 8) = *(uint4*)a0;
    *(uint4*)(P1 + (size_t)g * 8) = *(uint4*)a1;
}

// ---------------- fp16x2 MFMA GEMM (3 products, global_load_lds, XCD swizzle) ---------------
// C = act(ascale*(A@B^T)(+bias)). TM=128: wave 64x32 (MI=4); TM=64: wave 32x32 (MI=2).
// OUT: 0 = f32 C; 1 = fp16x2 A-planes (K2=N); 2 = f32 C + fused loss_res;
//      3 = fp16 row-major C (gather buffer); 5 = f32 C + fp16 row-major C.
template <int TM, int ACT, int OUT>
__launch_bounds__(256)
__global__ void mfma_gemm_kernel(const unsigned short* __restrict__ A0, const unsigned short* __restrict__ A1,
                                 const unsigned short* __restrict__ B0, const unsigned short* __restrict__ B1,
                                 const float* __restrict__ bias, int K, int N, float ascale,
                                 float* __restrict__ Cf,
                                 unsigned short* __restrict__ C0, unsigned short* __restrict__ C1,
                                 unsigned short* __restrict__ Ch,
                                 const float* __restrict__ Xref, float* __restrict__ accum) {
    constexpr int MI  = TM / 32;
    constexpr int APL = TM * 32;                  // ushorts per A-plane K-tile in LDS
    constexpr int ASEG = TM / 16;                 // 1KB segments per A plane
    __shared__ __align__(16) unsigned short lds[2 * APL + 4096];
    const int tid = threadIdx.x, lane = tid & 63, wv = tid >> 6;
    const int KT = K >> 5;
    // XCD-chunked swizzle: 8 consecutive-id blocks share one XCD -> A-panel L2-resident.
    const int nx = gridDim.x;
    const int id = blockIdx.y * nx + blockIdx.x;
    const int cpx = (nx * gridDim.y) >> 3;
    const int lid = (id & 7) * cpx + (id >> 3);
    const int bxx = lid % nx, byy = lid / nx;
    const int bm = byy * TM, bn = bxx * 64;
    const int wr = (wv >> 1) * (TM / 2), wc = (wv & 1) * 32;
    const int lr = lane & 15, cch = lane >> 4;

    const size_t abase = (size_t)(bm >> 7) * KT * 4096 + (bm & 127) * 32;
    const unsigned short* Ap[2] = {A0 + abase, A1 + abase};
    const unsigned short* Bp[2] = {B0 + (size_t)bxx * KT * 2048, B1 + (size_t)bxx * KT * 2048};
    int offA[MI], offB[2];
    #pragma unroll
    for (int mi = 0; mi < MI; ++mi) { int r = wr + mi * 16 + lr; offA[mi] = r * 32 + (((cch + (r >> 1)) & 3) << 3); }
    #pragma unroll
    for (int ni = 0; ni < 2; ++ni) { int r = wc + ni * 16 + lr; offB[ni] = r * 32 + (((cch + (r >> 1)) & 3) << 3); }

    f32x4 acc[MI][2];
    #pragma unroll
    for (int i = 0; i < MI; ++i)
        #pragma unroll
        for (int j = 0; j < 2; ++j) acc[i][j] = (f32x4){0.f, 0.f, 0.f, 0.f};

    for (int tk = 0; tk < KT; ++tk) {
        #pragma unroll
        for (int i = 0; i < 2 * ASEG / 4; ++i) {
            int s = i * 4 + wv, p = s / ASEG, q = s % ASEG;
            gload_lds16(Ap[p] + (size_t)tk * 4096 + q * 512 + lane * 8, &lds[p * APL + q * 512]);
        }
        #pragma unroll
        for (int i = 0; i < 2; ++i) {
            int s = i * 4 + wv, p = s >> 2, q = s & 3;
            gload_lds16(Bp[p] + (size_t)tk * 2048 + q * 512 + lane * 8, &lds[2 * APL + p * 2048 + q * 512]);
        }
        __syncthreads();
        f16x8 af[2][MI], bfr[2][2];
        #pragma unroll
        for (int p = 0; p < 2; ++p) {
            #pragma unroll
            for (int mi = 0; mi < MI; ++mi) af[p][mi] = *(const f16x8*)&lds[p * APL + offA[mi]];
            #pragma unroll
            for (int ni = 0; ni < 2; ++ni) bfr[p][ni] = *(const f16x8*)&lds[2 * APL + p * 2048 + offB[ni]];
        }
        #pragma unroll
        for (int mi = 0; mi < MI; ++mi)
            #pragma unroll
            for (int ni = 0; ni < 2; ++ni) {
                f32x4 c = acc[mi][ni];
                c = __builtin_amdgcn_mfma_f32_16x16x32_f16(af[0][mi], bfr[0][ni], c, 0, 0, 0);
                c = __builtin_amdgcn_mfma_f32_16x16x32_f16(af[0][mi], bfr[1][ni], c, 0, 0, 0);
                c = __builtin_amdgcn_mfma_f32_16x16x32_f16(af[1][mi], bfr[0][ni], c, 0, 0, 0);
                acc[mi][ni] = c;
            }
        __syncthreads();
    }
    float local = 0.f;
    #pragma unroll
    for (int mi = 0; mi < MI; ++mi)
        #pragma unroll
        for (int ni = 0; ni < 2; ++ni) {
            const int colg = bn + wc + ni * 16 + lr;
            #pragma unroll
            for (int r = 0; r < 4; ++r) {
                const int rowg = bm + wr + mi * 16 + cch * 4 + r;
                float v = acc[mi][ni][r] * ascale;
                if (ACT) { v += bias[colg]; v = 1.f / (1.f + __expf(-v)); }
                const size_t o = (size_t)rowg * N + colg;
                if (OUT == 0) {
                    Cf[o] = v;
                } else if (OUT == 1) {
                    size_t po = a_plane_off(rowg, colg, N);
                    unsigned short h0, h1; split2(v, h0, h1);
                    C0[po] = h0; C1[po] = h1;
                } else if (OUT == 2) {
                    Cf[o] = v;
                    float x = Xref[o];
                    float d = (v - x) * fmaf(x, 24.f, 1.f);
                    local = fmaf(d, d, local);
                } else if (OUT == 3) {
                    Ch[o] = f2h(v);
                } else {                           // OUT == 5
                    Cf[o] = v;
                    Ch[o] = f2h(v);
                }
            }
        }
    if (OUT == 2) {
        float* sred = (float*)lds;
        sred[tid] = local; __syncthreads();
        for (int s = 128; s; s >>= 1) { if (tid < s) sred[tid] += sred[tid + s]; __syncthreads(); }
        if (tid == 0) atomicAdd(accum, sred[0]);
    }
}

// ---------------- adj @ Mh (fp16) gather-sum + bias + lrelu ---------------------------------
// Gathers fp16 rows (half traffic vs f32), sums in f32. Lane owns 8 consecutive cols (16B).
// OUTF: f32 out (+ optional scalar out2). OUTP: emit fp16x2 A-planes of v*2^-6 (K=C).
template <int C, int OUTF, int OUTP>
__global__ void spmm_kernel(const unsigned short* __restrict__ Mh, const int* __restrict__ ell,
                            const int* __restrict__ cnt, const float* __restrict__ bias,
                            float* __restrict__ out, float* __restrict__ out2,
                            unsigned short* __restrict__ P0, unsigned short* __restrict__ P1) {
    constexpr int TPR = C / 8;
    constexpr int RPB = 256 / TPR;
    const int rid = threadIdx.x / TPR;
    const int c8  = threadIdx.x % TPR;
    const int row = blockIdx.x * RPB + rid;
    __shared__ int nb_s[RPB][ELL_W];
    const int n = cnt[row];
    for (int t = c8; t < n; t += TPR) nb_s[rid][t] = ell[row * ELL_W + t];
    __syncthreads();
    float acc[8] = {};
    for (int t = 0; t < n; ++t) {
        const f16x8 v = *(const f16x8*)(Mh + (size_t)nb_s[rid][t] * C + c8 * 8);
        #pragma unroll
        for (int j = 0; j < 8; ++j) acc[j] += (float)v[j];
    }
    float r[8];
    const float4 b0 = *(const float4*)(bias + c8 * 8);
    const float4 b1 = *(const float4*)(bias + c8 * 8 + 4);
    r[0] = lrelu(acc[0] + b0.x); r[1] = lrelu(acc[1] + b0.y);
    r[2] = lrelu(acc[2] + b0.z); r[3] = lrelu(acc[3] + b0.w);
    r[4] = lrelu(acc[4] + b1.x); r[5] = lrelu(acc[5] + b1.y);
    r[6] = lrelu(acc[6] + b1.z); r[7] = lrelu(acc[7] + b1.w);
    if (OUTF) {
        *(float4*)(out + (size_t)row * C + c8 * 8) = *(float4*)&r[0];
        *(float4*)(out + (size_t)row * C + c8 * 8 + 4) = *(float4*)&r[4];
        if (out2) {                               // +4B-misaligned d_out region: scalar
            size_t o = (size_t)row * C + c8 * 8;
            #pragma unroll
            for (int j = 0; j < 8; ++j) out2[o + j] = r[j];
        }
    }
    if (OUTP) {
        int tm = row >> 7, rr = row & 127;
        int tk = c8 >> 2, cc = c8 & 3;
        int pc = (cc + (rr >> 1)) & 3;
        size_t off = ((size_t)tm * (C >> 5) + tk) * 4096 + rr * 32 + pc * 8;
        unsigned short q0[8], q1[8];
        #pragma unroll
        for (int j = 0; j < 8; ++j) split2(r[j] * ASCL, q0[j], q1[j]);
        *(uint4*)(P0 + off) = *(uint4*)q0;
        *(uint4*)(P1 + off) = *(uint4*)q1;
    }
}

// ---------------- f1 = seq@a1, f2 = seq@a2 (f32 seq_fts — logits need full precision) -------
__global__ void f12_kernel(const float* __restrict__ seq, const float* __restrict__ a1,
                           const float* __restrict__ a2, float* __restrict__ f1,
                           float* __restrict__ f2) {
    const int row = blockIdx.x * 4 + (threadIdx.x >> 6);
    const int lane = threadIdx.x & 63;
    const float4 v  = *(const float4*)(seq + (size_t)row * 256 + lane * 4);
    const float4 w1 = *(const float4*)(a1 + lane * 4);
    const float4 w2 = *(const float4*)(a2 + lane * 4);
    float s1 = v.x * w1.x + v.y * w1.y + v.z * w1.z + v.w * w1.w;
    float s2 = v.x * w2.x + v.y * w2.y + v.z * w2.z + v.w * w2.w;
    #pragma unroll
    for (int o = 32; o; o >>= 1) { s1 += __shfl_xor(s1, o); s2 += __shfl_xor(s2, o); }
    if (lane == 0) { f1[row] = s1; f2[row] = s2; }
}

// ---------------- sparse GAT: f32 logits, fp16 PV gather -> fp16x2 A-planes (K=256) ---------
__global__ void attn_kernel(const unsigned short* __restrict__ seqh, const int* __restrict__ ell,
                            const int* __restrict__ cnt, const float* __restrict__ f1,
                            const float* __restrict__ f2,
                            unsigned short* __restrict__ P0, unsigned short* __restrict__ P1) {
    const int wid = threadIdx.x >> 6, lane = threadIdx.x & 63;
    const int row = blockIdx.x * 4 + wid;
    __shared__ int   nb_s[4][ELL_W];
    __shared__ float cf_s[4][ELL_W];
    const int n = cnt[row];
    const float f1r = f1[row];
    float m = -3.0e38f;
    for (int t = lane; t < n; t += 64) {
        int j = ell[row * ELL_W + t];
        nb_s[wid][t] = j;
        float v = lrelu(f1r + f2[j]);
        cf_s[wid][t] = v;
        m = fmaxf(m, v);
    }
    #pragma unroll
    for (int o = 32; o; o >>= 1) m = fmaxf(m, __shfl_xor(m, o));
    __syncthreads();
    float s = 0.f;
    for (int t = lane; t < n; t += 64) {
        float e = __expf(cf_s[wid][t] - m);
        cf_s[wid][t] = e;
        s += e;
    }
    #pragma unroll
    for (int o = 32; o; o >>= 1) s += __shfl_xor(s, o);
    const float inv = 1.f / s;
    __syncthreads();
    float acc[4] = {};
    for (int t = 0; t < n; ++t) {
        const float c = cf_s[wid][t];
        const f16x4 v = *(const f16x4*)(seqh + (size_t)nb_s[wid][t] * 256 + lane * 4);
        #pragma unroll
        for (int j = 0; j < 4; ++j) acc[j] = fmaf(c, (float)v[j], acc[j]);
    }
    float r[4];
    #pragma unroll
    for (int j = 0; j < 4; ++j) r[j] = lrelu(acc[j] * inv);
    int tm = row >> 7, rr = row & 127;
    int tk = lane >> 3, cc = (lane >> 1) & 3, h = lane & 1;
    int pc = (cc + (rr >> 1)) & 3;
    size_t off = ((size_t)tm * 8 + tk) * 4096 + rr * 32 + pc * 8 + h * 4;
    ushort4 q0, q1;
    split2(r[0] * ASCL, q0.x, q1.x); split2(r[1] * ASCL, q0.y, q1.y);
    split2(r[2] * ASCL, q0.z, q1.z); split2(r[3] * ASCL, q0.w, q1.w);
    *(ushort4*)(P0 + off) = q0; *(ushort4*)(P1 + off) = q1;
}

// ---------------- loss_emb (f32 H — keeps reference-grade loss) -----------------------------
__global__ void loss_emb_kernel(const float* __restrict__ H, const int* __restrict__ ell,
                                const int* __restrict__ cnt, const float* __restrict__ deg,
                                float* __restrict__ accum) {
    const int row = blockIdx.x, tid = threadIdx.x;
    __shared__ int nb[ELL_W];
    __shared__ float sred[128];
    const int n = cnt[row];
    if (tid < n) nb[tid] = ell[row * ELL_W + tid];
    __syncthreads();
    float hv = H[(size_t)row * 128 + tid];
    float g = 0.f;
    for (int t = 0; t < n; ++t) g += H[(size_t)nb[t] * 128 + tid];
    float lh = deg[row] * hv - g;
    sred[tid] = hv * lh; __syncthreads();
    for (int s = 64; s; s >>= 1) { if (tid < s) sred[tid] += sred[tid + s]; __syncthreads(); }
    if (tid == 0) atomicAdd(accum + 1, sred[0]);
}

__global__ void finalize_kernel(const float* __restrict__ accum, float* __restrict__ out) {
    out[0] = 100.f * accum[0] + 2.f * accum[1];
}

// ---------------- driver --------------------------------------------------------------------
extern "C" void kernel_launch(void* const* d_in, const int* in_sizes, int n_in,
                              void* d_out, int out_size, void* d_ws, size_t ws_size,
                              hipStream_t stream) {
    const float* X      = (const float*)d_in[0];
    const float* adj    = (const float*)d_in[1];
    const float* W0     = (const float*)d_in[2];
    const float* b0     = (const float*)d_in[3];
    const float* W1     = (const float*)d_in[4];
    const float* b1     = (const float*)d_in[5];
    const float* W2     = (const float*)d_in[6];
    const float* b2     = (const float*)d_in[7];
    const float* attn_W = (const float*)d_in[8];
    const float* a1     = (const float*)d_in[9];
    const float* a2     = (const float*)d_in[10];
    const float* dW0    = (const float*)d_in[11];
    const float* db0    = (const float*)d_in[12];
    const float* dW1    = (const float*)d_in[13];
    const float* db1    = (const float*)d_in[14];
    const float* dW2    = (const float*)d_in[15];
    const float* db2    = (const float*)d_in[16];

    float* out  = (float*)d_out;
    float* Hout = out + 1;
    float* Xr   = out + 1 + (size_t)NN * 128;

    char* w = (char*)d_ws;
    int*   ell   = (int*)w;   w += (size_t)NN * ELL_W * 4;
    int*   cnt   = (int*)w;   w += (size_t)NN * 4;
    float* deg   = (float*)w; w += (size_t)NN * 4;
    float* f1    = (float*)w; w += (size_t)NN * 4;
    float* f2    = (float*)w; w += (size_t)NN * 4;
    float* accum = (float*)w; w += 256;
    float* bufB  = (float*)w; w += (size_t)NN * 256 * 4;      // seq_fts f32 (f12 logits)
    float* bufH  = (float*)w; w += (size_t)NN * 128 * 4;      // H f32 (loss_emb)
    unsigned short* XW0h = (unsigned short*)w; w += (size_t)NN * 512 * 2;   // fp16 gather bufs
    unsigned short* T1h  = (unsigned short*)w; w += (size_t)NN * 256 * 2;
    unsigned short* T2h  = (unsigned short*)w; w += (size_t)NN * 128 * 2;
    unsigned short* seqh = (unsigned short*)w; w += (size_t)NN * 256 * 2;
    unsigned short *XP[2], *W0T[2], *h0P[2], *W1T[2], *h1P[2], *aWR[2], *h2P[2], *W2T[2];
    unsigned short *HP[2], *dW0T[2], *R0P[2], *dW1T[2], *R1P[2], *dW2T[2];
    for (int i = 0; i < 2; ++i) { XP[i]   = (unsigned short*)w; w += (size_t)NN * 1024 * 2; }
    for (int i = 0; i < 2; ++i) { W0T[i]  = (unsigned short*)w; w += (size_t)512 * 1024 * 2; }
    for (int i = 0; i < 2; ++i) { h0P[i]  = (unsigned short*)w; w += (size_t)NN * 512 * 2; }
    for (int i = 0; i < 2; ++i) { W1T[i]  = (unsigned short*)w; w += (size_t)256 * 512 * 2; }
    for (int i = 0; i < 2; ++i) { h1P[i]  = (unsigned short*)w; w += (size_t)NN * 256 * 2; }
    for (int i = 0; i < 2; ++i) { aWR[i]  = (unsigned short*)w; w += (size_t)256 * 256 * 2; }
    for (int i = 0; i < 2; ++i) { h2P[i]  = (unsigned short*)w; w += (size_t)NN * 256 * 2; }
    for (int i = 0; i < 2; ++i) { W2T[i]  = (unsigned short*)w; w += (size_t)128 * 256 * 2; }
    for (int i = 0; i < 2; ++i) { HP[i]   = (unsigned short*)w; w += (size_t)NN * 128 * 2; }
    for (int i = 0; i < 2; ++i) { dW0T[i] = (unsigned short*)w; w += (size_t)256 * 128 * 2; }
    for (int i = 0; i < 2; ++i) { R0P[i]  = (unsigned short*)w; w += (size_t)NN * 256 * 2; }
    for (int i = 0; i < 2; ++i) { dW1T[i] = (unsigned short*)w; w += (size_t)512 * 256 * 2; }
    for (int i = 0; i < 2; ++i) { R1P[i]  = (unsigned short*)w; w += (size_t)NN * 512 * 2; }
    for (int i = 0; i < 2; ++i) { dW2T[i] = (unsigned short*)w; w += (size_t)1024 * 512 * 2; }

    build_ell_kernel<<<dim3(NN / 4), dim3(256), 0, stream>>>(adj, ell, cnt, deg);
    zero_accum_kernel<<<1, 1, 0, stream>>>(accum);

    // splits (fp16x2, tiled-swizzled planes; X/weights unscaled — all bounded ~6)
    splitA_kernel<<<4096, 256, 0, stream>>>(X, XP[0], XP[1], 1024, NN * 1024 / 8);
    splitBT_kernel<<<256, 256, 0, stream>>>(W0, W0T[0], W0T[1], 1024, 512, 512 * 1024 / 8);
    splitBT_kernel<<<64, 256, 0, stream>>>(W1, W1T[0], W1T[1], 512, 256, 256 * 512 / 8);
    splitBR_kernel<<<32, 256, 0, stream>>>(attn_W, aWR[0], aWR[1], 256, 256 * 256 / 8);
    splitBT_kernel<<<16, 256, 0, stream>>>(W2, W2T[0], W2T[1], 256, 128, 128 * 256 / 8);
    splitBT_kernel<<<16, 256, 0, stream>>>(dW0, dW0T[0], dW0T[1], 128, 256, 256 * 128 / 8);
    splitBT_kernel<<<64, 256, 0, stream>>>(dW1, dW1T[0], dW1T[1], 256, 512, 512 * 256 / 8);
    splitBT_kernel<<<256, 256, 0, stream>>>(dW2, dW2T[0], dW2T[1], 512, 1024, 1024 * 512 / 8);

    // 1. XW0 = X @ W0 (K=1024, N=512), TM=128 -> fp16 gather buffer
    mfma_gemm_kernel<128, 0, 3><<<dim3(8, 64), 256, 0, stream>>>(
        XP[0], XP[1], W0T[0], W0T[1], nullptr, 1024, 512, 1.f, nullptr, nullptr, nullptr, XW0h, nullptr, nullptr);
    // 2. h0 = lrelu(adj@XW0 + b0) -> planes (x2^-6)
    spmm_kernel<512, 0, 1><<<NN / 4, 256, 0, stream>>>(XW0h, ell, cnt, b0, nullptr, nullptr, h0P[0], h0P[1]);
    // 3. T1 = h0 @ W1 (K=512, N=256), TM=64, ascale=64 -> fp16 gather buffer
    mfma_gemm_kernel<64, 0, 3><<<dim3(4, 128), 256, 0, stream>>>(
        h0P[0], h0P[1], W1T[0], W1T[1], nullptr, 512, 256, 64.f, nullptr, nullptr, nullptr, T1h, nullptr, nullptr);
    // 4. h1 = lrelu(adj@T1 + b1) -> planes (x2^-6)
    spmm_kernel<256, 0, 1><<<NN / 8, 256, 0, stream>>>(T1h, ell, cnt, b1, nullptr, nullptr, h1P[0], h1P[1]);
    // 5. seq_fts = h1 @ attn_W^T (K=256, N=256), TM=64, ascale=64 -> f32 (logits) + fp16 (PV)
    mfma_gemm_kernel<64, 0, 5><<<dim3(4, 128), 256, 0, stream>>>(
        h1P[0], h1P[1], aWR[0], aWR[1], nullptr, 256, 256, 64.f, bufB, nullptr, nullptr, seqh, nullptr, nullptr);
    // 6. f1, f2 (from f32 seq_fts)
    f12_kernel<<<NN / 4, 256, 0, stream>>>(bufB, a1, a2, f1, f2);
    // 7. h2 = attention (fp16 PV gather) -> planes (x2^-6)
    attn_kernel<<<NN / 4, 256, 0, stream>>>(seqh, ell, cnt, f1, f2, h2P[0], h2P[1]);
    // 8. T2 = h2 @ W2 (K=256, N=128), TM=64, ascale=64 -> fp16 gather buffer
    mfma_gemm_kernel<64, 0, 3><<<dim3(2, 128), 256, 0, stream>>>(
        h2P[0], h2P[1], W2T[0], W2T[1], nullptr, 256, 128, 64.f, nullptr, nullptr, nullptr, T2h, nullptr, nullptr);
    // 9. H = lrelu(adj@T2 + b2) -> f32 (bufH + Hout) + planes (x2^-6)
    spmm_kernel<128, 1, 1><<<NN / 16, 256, 0, stream>>>(T2h, ell, cnt, b2, bufH, Hout, HP[0], HP[1]);
    // 10. Xr0 = sigmoid(64*(H/64 @ dW0) + db0) (K=128, N=256), TM=64 -> planes
    mfma_gemm_kernel<64, 1, 1><<<dim3(4, 128), 256, 0, stream>>>(
        HP[0], HP[1], dW0T[0], dW0T[1], db0, 128, 256, 64.f, nullptr, R0P[0], R0P[1], nullptr, nullptr, nullptr);
    // 11. Xr1 = sigmoid(Xr0 @ dW1 + db1) (K=256, N=512), TM=128 -> planes
    mfma_gemm_kernel<128, 1, 1><<<dim3(8, 64), 256, 0, stream>>>(
        R0P[0], R0P[1], dW1T[0], dW1T[1], db1, 256, 512, 1.f, nullptr, R1P[0], R1P[1], nullptr, nullptr, nullptr);
    // 12. Xr = sigmoid(Xr1 @ dW2 + db2) (K=512, N=1024), TM=128 -> f32 Xr + fused loss_res
    mfma_gemm_kernel<128, 1, 2><<<dim3(16, 64), 256, 0, stream>>>(
        R1P[0], R1P[1], dW2T[0], dW2T[1], db2, 512, 1024, 1.f, Xr, nullptr, nullptr, nullptr, X, accum);
    // 13. loss_emb + finalize
    loss_emb_kernel<<<NN, 128, 0, stream>>>(bufH, ell, cnt, deg, accum);
    finalize_kernel<<<1, 1, 0, stream>>>(accum, out);
}